// Round 15
// baseline (95.387 us; speedup 1.0000x reference)
//
#include <hip/hip_runtime.h>

// ---------------------------------------------------------------------------
// Native Sparse Attention (B=2, H=8, S=2048, D=64)
// == R12-PASSING kernel + ONE change: stage barriers fused into a single
// opaque asm blob (s_waitcnt vmcnt(N) lgkmcnt(0) + s_barrier, "memory")
// so no LDS read can be hoisted across the barrier at IR or MIR level. ==
// NO grid swizzle (identified as a race trigger in R13/R14 — parked).
// Prep: nsa_cvt builds bf16 PRE-SWIZZLED 8KB tiles K16[bh][blk][tok][dim],
// VT16[bh][blk][dim][tok] (+ exact f32 block means); nsa_group (64 thr,
// serial, known-good) does exact fp32 factorized top-8 per 64-query group
// + K̄/V̄T bf16 tiles (k0/v0 folded). Main: block = 32 queries (4 waves x
// 8q), grid (64,16). 24 stages; ring-3 LDS staging via global_load_lds;
// counted vmcnt(2) per stage (vmcnt(0) only at the last stage).
// Wave reductions: 4 valid DPP hops (intra-16) + 2 shfl_xor (cross-row).
// ---------------------------------------------------------------------------

constexpr int SS   = 2048;
constexpr int DD   = 64;
constexpr int NBLK = 32;
constexpr int BS   = 64;
constexpr int SNB  = 8;
constexpr int KKEEP = 256;
constexpr float SCALE  = 0.125f;
constexpr float NEGINF = -1e30f;

#define DEV __device__ __forceinline__

typedef __attribute__((ext_vector_type(8))) short s8_t;   // 8 x bf16
typedef __attribute__((ext_vector_type(4))) float f4_t;   // MFMA C/D frag

union S8U { uint4 u; s8_t s; };

DEV s8_t as_s8(uint4 u) { S8U x; x.u = u; return x.s; }
DEV s8_t s8zero() { uint4 z = {0, 0, 0, 0}; return as_s8(z); }

DEV float readlane_f(float x, int l) {
  return __int_as_float(__builtin_amdgcn_readlane(__float_as_int(x), l));
}
template <int CTRL>
DEV float dpp_mv(float x, float old) {
  return __int_as_float(__builtin_amdgcn_update_dpp(
      __float_as_int(old), __float_as_int(x), CTRL, 0xf, 0xf, false));
}
// wave64 reductions: intra-16 via VALID CDNA DPP controls, cross-row shfl.
DEV float wave_max(float x) {
  x = fmaxf(x, dpp_mv<0xB1>(x, x));
  x = fmaxf(x, dpp_mv<0x4E>(x, x));
  x = fmaxf(x, dpp_mv<0x141>(x, x));
  x = fmaxf(x, dpp_mv<0x140>(x, x));
  x = fmaxf(x, __shfl_xor(x, 16, 64));
  x = fmaxf(x, __shfl_xor(x, 32, 64));
  return x;
}
DEV float wave_sum(float x) {
  x += dpp_mv<0xB1>(x, 0.f);
  x += dpp_mv<0x4E>(x, 0.f);
  x += dpp_mv<0x141>(x, 0.f);
  x += dpp_mv<0x140>(x, 0.f);
  x += __shfl_xor(x, 16, 64);
  x += __shfl_xor(x, 32, 64);
  return x;
}
DEV unsigned cvt_pk(float lo, float hi) {
  unsigned d;
  asm("v_cvt_pk_bf16_f32 %0, %1, %2" : "=v"(d) : "v"(lo), "v"(hi));
  return d;
}
DEV f4_t mfma16(s8_t a, s8_t b, f4_t c) {
  return __builtin_amdgcn_mfma_f32_16x16x32_bf16(a, b, c, 0, 0, 0);
}
DEV void wave_fence() {
  asm volatile("s_waitcnt lgkmcnt(0)" ::: "memory");
  __builtin_amdgcn_sched_barrier(0);
}
// HARDENED stage barriers: wait + s_barrier fused in ONE opaque volatile asm
// with "memory" clobber -> indivisible; no load can be hoisted across the
// barrier by IR passes or the machine scheduler. vmcnt(2) keeps the next
// tile's 2 DMAs in flight; vmcnt(0) only at the final stage.
DEV void dma_bar2() {
  asm volatile("s_waitcnt vmcnt(2) lgkmcnt(0)\n\ts_barrier" ::: "memory");
  __builtin_amdgcn_sched_barrier(0);
}
DEV void dma_bar0() {
  asm volatile("s_waitcnt vmcnt(0) lgkmcnt(0)\n\ts_barrier" ::: "memory");
  __builtin_amdgcn_sched_barrier(0);
}

// swizzled uint index within an 8KB tile: row 0..63, chunk 0..7 (16B chunks)
DEV int swz(int row, int chunk) { return row * 32 + (((chunk) ^ (row & 7)) << 2); }

typedef __attribute__((address_space(1))) const unsigned GU;
typedef __attribute__((address_space(3))) unsigned LU;
// stage one 8KB tile: 4 waves x 2 instr x 64 lanes x 16B (linear copy)
DEV void stage_dma(const unsigned* tile, unsigned* lbuf, int w, int lane) {
#pragma unroll
  for (int j = 0; j < 2; ++j) {
    const unsigned* src = tile + ((w * 2 + j) * 64 + lane) * 4;
    __builtin_amdgcn_global_load_lds((GU*)src, (LU*)(lbuf + (w * 2 + j) * 256),
                                     16, 0, 0);
  }
}

// 8 MFMA from swizzled LDS tile (B rows = tokens for QK / dims for PV)
DEV void mm8_lds(const unsigned* buf, const s8_t A[2], int qi, int g, f4_t c[4]) {
#pragma unroll
  for (int t = 0; t < 4; ++t) {
    f4_t acc = {0.f, 0.f, 0.f, 0.f};
#pragma unroll
    for (int ks = 0; ks < 2; ++ks) {
      const s8_t B = as_s8(*(const uint4*)(buf + swz(t * 16 + qi, ks * 4 + g)));
      acc = mfma16(A[ks], B, acc);
    }
    c[t] = acc;
  }
}
DEV void mm8acc_lds(const unsigned* buf, const s8_t A[2], int qi, int g, f4_t Of[4]) {
#pragma unroll
  for (int ks = 0; ks < 2; ++ks) {
#pragma unroll
    for (int t = 0; t < 4; ++t) {
      const s8_t B = as_s8(*(const uint4*)(buf + swz(t * 16 + qi, ks * 4 + g)));
      Of[t] = mfma16(A[ks], B, Of[t]);
    }
  }
}

// redistribute C frags (q rows 0..7) -> per-lane raw[j], lane = col 0..63.
// col-major scratch [col 64][row 8]: 4x ds_write_b128 + 2x ds_read_b128.
DEV void redist(const f4_t c[4], float* scw, int lane, float raw[8]) {
  if (lane < 32) {
    const int g2 = lane >> 4, ci = lane & 15;
#pragma unroll
    for (int t = 0; t < 4; ++t)
      *(f4_t*)(scw + (t * 16 + ci) * 8 + g2 * 4) = c[t];
  }
  wave_fence();
  *(f4_t*)(raw)     = *(const f4_t*)(scw + lane * 8);
  *(f4_t*)(raw + 4) = *(const f4_t*)(scw + lane * 8 + 4);
}

// ---- ws layout (4-byte element offsets) ----
constexpr size_t OFF_KBLK  = 0;         // f32 16*32*64
constexpr size_t OFF_VBLK  = 32768;     // f32 16*32*64
constexpr size_t OFF_SEL   = 65536;     // int 16*32*8
constexpr size_t OFF_KBAR  = 69632;     // u32 16*2048 (swizzled tiles)
constexpr size_t OFF_VBART = 102400;    // u32 16*2048
constexpr size_t OFF_K16   = 135168;    // u32 16*32*2048
constexpr size_t OFF_VT16  = 1183744;   // u32 16*32*2048

// ---------------------------------------------------------------------------
// Prep 1: bf16 swizzled K/V tiles + exact f32 block means
__global__ __launch_bounds__(256) void nsa_cvt(
    const float* __restrict__ kg, const float* __restrict__ vg,
    float* __restrict__ kblk, float* __restrict__ vblk,
    unsigned* __restrict__ K16, unsigned* __restrict__ VT16) {
  const int blk = blockIdx.x, bh = blockIdx.y, tid = threadIdx.x;
  __shared__ float kl[64][65], vl[64][65];
  const size_t tb = ((size_t)bh * SS + (size_t)blk * BS) * DD;
  unsigned* Kt = K16 + ((size_t)bh * NBLK + blk) * 2048;
  unsigned* Vt = VT16 + ((size_t)bh * NBLK + blk) * 2048;
#pragma unroll
  for (int m = 0; m < 4; ++m) {
    const int f4i = tid + 256 * m;
    const int r = f4i >> 4, c = f4i & 15;
    const float4 kk = *(const float4*)(kg + tb + r * DD + c * 4);
    const float4 vv = *(const float4*)(vg + tb + r * DD + c * 4);
    kl[r][c * 4] = kk.x; kl[r][c * 4 + 1] = kk.y;
    kl[r][c * 4 + 2] = kk.z; kl[r][c * 4 + 3] = kk.w;
    vl[r][c * 4] = vv.x; vl[r][c * 4 + 1] = vv.y;
    vl[r][c * 4 + 2] = vv.z; vl[r][c * 4 + 3] = vv.w;
    const int a = r * 32 + (((c >> 1) ^ (r & 7)) << 2) + (c & 1) * 2;
    Kt[a]     = cvt_pk(kk.x, kk.y);
    Kt[a + 1] = cvt_pk(kk.z, kk.w);
  }
  __syncthreads();
  const int d = tid >> 2, cg = tid & 3;
#pragma unroll
  for (int cc = 0; cc < 2; ++cc) {
    const int c = cg * 2 + cc;
#pragma unroll
    for (int w4 = 0; w4 < 4; ++w4) {
      const int tp = c * 4 + w4;
      Vt[d * 32 + ((c ^ (d & 7)) << 2) + w4] = cvt_pk(vl[2 * tp][d], vl[2 * tp + 1][d]);
    }
  }
  if (tid < DD) {
    float sk = 0.f, sv = 0.f;
#pragma unroll 8
    for (int t = 0; t < BS; ++t) { sk += kl[t][tid]; sv += vl[t][tid]; }
    kblk[((size_t)bh * NBLK + blk) * DD + tid] = sk * (1.f / 64.f);
    vblk[((size_t)bh * NBLK + blk) * DD + tid] = sv * (1.f / 64.f);
  }
}

// ---------------------------------------------------------------------------
// Prep 2 (64 threads, serial — known-good): exact fp32 factorized block
// scores + top-8 per group; gp==0 builds Kbar16 / VbarT16 tiles.
__global__ __launch_bounds__(64) void nsa_group(
    const float* __restrict__ qg, const float* __restrict__ kg,
    const float* __restrict__ vg, const float* __restrict__ kblk,
    const float* __restrict__ vblk, int* __restrict__ selidx,
    unsigned* __restrict__ Kbar16, unsigned* __restrict__ VbarT16) {
  const int gp = blockIdx.x, bh = blockIdx.y, d = threadIdx.x;
  __shared__ float qb_s[64];
  __shared__ float sc_s[32];
  {
    const float* qp = qg + ((size_t)bh * SS + (size_t)gp * 64) * DD + d;
    float s = 0.f;
    for (int r = 0; r < 64; ++r) s += qp[r * DD];
    qb_s[d] = s;
  }
  __syncthreads();
  if (d < 32) {
    const float* kr = kblk + ((size_t)bh * NBLK + d) * DD;
    float p = 0.f;
    for (int dd = 0; dd < 64; ++dd) p = fmaf(qb_s[dd], kr[dd], p);
    sc_s[d] = (d <= gp) ? p : NEGINF;
  }
  __syncthreads();
  if (d == 0) {
    unsigned taken = 0u;
    for (int t = 0; t < SNB; ++t) {
      float best = -3.4e38f; int bi = 0;
      for (int n = 0; n < NBLK; ++n)
        if (!((taken >> n) & 1u) && sc_s[n] > best) { best = sc_s[n]; bi = n; }
      taken |= 1u << bi;
      selidx[((size_t)bh * NBLK + gp) * SNB + t] = bi;
    }
  }
  if (gp == 0) {
    unsigned* Kt = Kbar16 + (size_t)bh * 2048;
    unsigned* Vt = VbarT16 + (size_t)bh * 2048;
    if (d < 32) {
      for (int n = 0; n < 32; ++n)
        Kt[n * 32 + (((d >> 2) ^ (n & 7)) << 2) + (d & 3)] =
            cvt_pk(kblk[((size_t)bh * NBLK + n) * DD + 2 * d],
                   kblk[((size_t)bh * NBLK + n) * DD + 2 * d + 1]);
      Kt[32 * 32 + ((d >> 2) << 2) + (d & 3)] =
          cvt_pk(kg[(size_t)bh * SS * DD + 2 * d],
                 kg[(size_t)bh * SS * DD + 2 * d + 1]);
      for (int n = 33; n < 64; ++n)
        Kt[n * 32 + (((d >> 2) ^ (n & 7)) << 2) + (d & 3)] = 0u;
    }
    for (int tp = 0; tp < 32; ++tp) {
      unsigned u = 0u;
      if (tp < 16)
        u = cvt_pk(vblk[((size_t)bh * NBLK + 2 * tp) * DD + d],
                   vblk[((size_t)bh * NBLK + 2 * tp + 1) * DD + d]);
      else if (tp == 16)
        u = cvt_pk(vg[(size_t)bh * SS * DD + d], 0.f);
      Vt[d * 32 + (((tp >> 2) ^ (d & 7)) << 2) + (tp & 3)] = u;
    }
  }
}

// ---------------------------------------------------------------------------
// Main: 24 stages, ring-3 staging, counted vmcnt, 2D grid (64,16).
__global__ __launch_bounds__(256) void nsa_main(
    const float* __restrict__ qg, const int* __restrict__ selp,
    const unsigned* __restrict__ Kbar16, const unsigned* __restrict__ VbarT16,
    const unsigned* __restrict__ K16, const unsigned* __restrict__ VT16,
    float* __restrict__ outg) {
  const int tid  = threadIdx.x;
  const int w    = tid >> 6;
  const int lane = tid & 63;
  const int qtile = blockIdx.x * 4 + w;     // 0..255 (8 queries each)
  const int bh    = blockIdx.y;
  const int gg    = blockIdx.x >> 1;        // 64-query group (block-uniform)
  const int q0    = qtile * 8;
  const size_t base = (size_t)bh * SS * DD;

  __shared__ __align__(16) unsigned buf_s[3][2048];  // 24 KB ring
  __shared__ __align__(16) float sc_f[4][576];       // per-wave scratch
  float* scw = sc_f[w];
  unsigned short* scwu = (unsigned short*)scw;
  const int qi = lane & 15, g = lane >> 4;
  const int qc = (qi < 8) ? qi : 0;

  const unsigned* K16b = K16 + (size_t)bh * NBLK * 2048;
  const unsigned* V16b = VT16 + (size_t)bh * NBLK * 2048;
  const int wb0 = (gg > 2) ? gg - 2 : 0;
  const int wb1 = (gg > 1) ? gg - 1 : 0;
  const int wb2 = gg;

  // ---- prologue: sel list, Q frags, first two tile DMAs ----
  int sel[SNB];
#pragma unroll
  for (int i = 0; i < SNB; ++i) sel[i] = selp[((size_t)bh * NBLK + gg) * SNB + i];
  s8_t qA[2];
  {
    const float* qr2 = qg + base + (size_t)(q0 + qc) * DD + g * 8;
    const float4 a0 = *(const float4*)(qr2);
    const float4 a1 = *(const float4*)(qr2 + 4);
    const float4 a2 = *(const float4*)(qr2 + 32);
    const float4 a3 = *(const float4*)(qr2 + 36);
    uint4 u0 = {cvt_pk(a0.x, a0.y), cvt_pk(a0.z, a0.w),
                cvt_pk(a1.x, a1.y), cvt_pk(a1.z, a1.w)};
    uint4 u1 = {cvt_pk(a2.x, a2.y), cvt_pk(a2.z, a2.w),
                cvt_pk(a3.x, a3.y), cvt_pk(a3.z, a3.w)};
    qA[0] = (qi < 8) ? as_s8(u0) : s8zero();
    qA[1] = (qi < 8) ? as_s8(u1) : s8zero();
  }
  // tiles 0 (K̄) and 1 (K sel[0])
  stage_dma(Kbar16 + (size_t)bh * 2048, buf_s[0], w, lane);
  stage_dma(K16b + (size_t)sel[0] * 2048, buf_s[1], w, lane);

  // ================= K phase =================
  unsigned cPp[4];
  float l192[8];
  // --- stage 0: K̄ (+k0 col 32) ---
  dma_bar2();
  stage_dma(K16b + (size_t)sel[1] * 2048, buf_s[2], w, lane);   // tile 2
  {
    f4_t c[4];
    mm8_lds(buf_s[0], qA, qi, g, c);
    float raw[8];
    redist(c, scw, lane, raw);
    float cPf[8];
#pragma unroll
    for (int j = 0; j < 8; ++j) {
      l192[j] = readlane_f(raw[j], 32) * SCALE;
      const bool valid = (lane < 32) && (lane <= gg);
      const float l = valid ? raw[j] * SCALE : NEGINF;
      const float m = wave_max(l);
      const float e = valid ? __expf(l - m) : 0.f;
      const float ss = wave_sum(e);
      cPf[j] = e / ss;
    }
#pragma unroll
    for (int ip = 0; ip < 4; ++ip) cPp[ip] = cvt_pk(cPf[2 * ip], cPf[2 * ip + 1]);
  }

  // --- stages 1..8: sel QK ---
  float L[8][SNB];
#pragma unroll
  for (int sbi = 0; sbi < SNB; ++sbi) {
    const int s = 1 + sbi;
    dma_bar2();
    const unsigned* nt = (sbi <= 5) ? (K16b + (size_t)sel[sbi + 2] * 2048)
                       : ((sbi == 6) ? (K16b + (size_t)wb0 * 2048)
                                     : (K16b + (size_t)wb1 * 2048));
    stage_dma(nt, buf_s[(s + 2) % 3], w, lane);
    f4_t c[4];
    mm8_lds(buf_s[s % 3], qA, qi, g, c);
    float raw[8];
    redist(c, scw, lane, raw);
    const int tok = sel[sbi] * BS + lane;
#pragma unroll
    for (int j = 0; j < 8; ++j)
      L[j][sbi] = (tok <= q0 + j) ? raw[j] * SCALE : NEGINF;
  }

  // ---- threshold (12-iter float-window) + sel softmax -> packed bf16 ----
  unsigned Lp[8][4];
#pragma unroll
  for (int j = 0; j < 8; ++j) {
    float m = L[j][0];
#pragma unroll
    for (int i = 1; i < SNB; ++i) m = fmaxf(m, L[j][i]);
    m = wave_max(m);
    float lo = m - 20.f, hi = m;
    int c0 = 0;
#pragma unroll
    for (int i = 0; i < SNB; ++i) c0 += __popcll(__ballot(L[j][i] >= lo));
    if (c0 >= KKEEP) {
      for (int it = 0; it < 12; ++it) {
        const float mid = 0.5f * (lo + hi);
        int cc = 0;
#pragma unroll
        for (int i = 0; i < SNB; ++i) cc += __popcll(__ballot(L[j][i] >= mid));
        if (cc >= KKEEP) lo = mid; else hi = mid;
      }
    }
    const float thr = lo;
    float s = 0.f;
#pragma unroll
    for (int i = 0; i < SNB; ++i) {
      const float e = (L[j][i] >= thr) ? __expf(L[j][i] - m) : 0.f;
      L[j][i] = e; s += e;
    }
    s = wave_sum(s);
    const float inv = 1.f / s;
#pragma unroll
    for (int ip = 0; ip < 4; ++ip)
      Lp[j][ip] = cvt_pk(L[j][2 * ip] * inv, L[j][2 * ip + 1] * inv);
  }

  // --- stages 9..11: win QK ---
  float Lw[8][3];
#pragma unroll
  for (int wi = 0; wi < 3; ++wi) {
    const int s = 9 + wi;
    const int wb = gg - 2 + wi;
    dma_bar2();
    const unsigned* nt = (wi == 0) ? (K16b + (size_t)wb2 * 2048)
                       : ((wi == 1) ? (VbarT16 + (size_t)bh * 2048)
                                    : (V16b + (size_t)sel[0] * 2048));
    stage_dma(nt, buf_s[(s + 2) % 3], w, lane);
    f4_t c[4];
    mm8_lds(buf_s[s % 3], qA, qi, g, c);
    float raw[8];
    redist(c, scw, lane, raw);
    const int tok = wb * BS + lane;
#pragma unroll
    for (int j = 0; j < 8; ++j) {
      const int pos = q0 + j;
      const bool valid = (wb >= 0) && (tok <= pos) && ((pos - tok < 128) || (tok == 0));
      Lw[j][wi] = valid ? raw[j] * SCALE : NEGINF;
    }
  }

  // ---- win softmax ----
  unsigned Lwp[8][2];
  float p192[8];
#pragma unroll
  for (int j = 0; j < 8; ++j) {
    const float l1 = (gg >= 3) ? l192[j] : NEGINF;
    float m = fmaxf(fmaxf(Lw[j][0], Lw[j][1]), Lw[j][2]);
    m = wave_max(m);
    m = fmaxf(m, l1);
    const float e0 = __expf(Lw[j][0] - m);
    const float e1 = __expf(Lw[j][1] - m);
    const float e2 = __expf(Lw[j][2] - m);
    float s = wave_sum(e0 + e1 + e2);
    const float e192 = (gg >= 3) ? __expf(l1 - m) : 0.f;
    s += e192;
    const float inv = 1.f / s;
    Lwp[j][0] = cvt_pk(e0 * inv, e1 * inv);
    Lwp[j][1] = cvt_pk(e2 * inv, 0.f);
    p192[j] = e192 * inv;
  }

  // ================= V phase =================
  f4_t Of[4];
#pragma unroll
  for (int t = 0; t < 4; ++t) Of[t] = (f4_t){0.f, 0.f, 0.f, 0.f};
  s8_t Pa[2];

  // --- stage 12: V̄ (cmp PV + global token at tok 32) ---
  dma_bar2();
  stage_dma(V16b + (size_t)sel[1] * 2048, buf_s[(12 + 2) % 3], w, lane); // tile 14
#pragma unroll
  for (int j = 0; j < 8; ++j) {
    const unsigned uu = cPp[j >> 1];
    unsigned short pv = (unsigned short)((j & 1) ? (uu >> 16) : (uu & 0xffffu));
    if (lane == 32) pv = (unsigned short)(cvt_pk(p192[j], 0.f) & 0xffffu);
    else if (lane > 32) pv = 0;
    scwu[j * 136 + lane] = pv;
  }
  wave_fence();
#pragma unroll
  for (int ks = 0; ks < 2; ++ks) {
    Pa[ks] = as_s8(*(const uint4*)(scwu + qc * 136 + ks * 32 + g * 8));
    if (qi >= 8) Pa[ks] = s8zero();
  }
  mm8acc_lds(buf_s[12 % 3], Pa, qi, g, Of);

  // --- stages 13..20: sel PV ---
#pragma unroll
  for (int sbi = 0; sbi < SNB; ++sbi) {
    const int s = 13 + sbi;
    dma_bar2();
    const unsigned* nt = (sbi <= 5) ? (V16b + (size_t)sel[sbi + 2] * 2048)
                       : ((sbi == 6) ? (V16b + (size_t)wb0 * 2048)
                                     : (V16b + (size_t)wb1 * 2048));
    stage_dma(nt, buf_s[(s + 2) % 3], w, lane);
#pragma unroll
    for (int j = 0; j < 8; ++j) {
      const unsigned uu = Lp[j][sbi >> 1];
      scwu[j * 136 + lane] = (unsigned short)((sbi & 1) ? (uu >> 16) : (uu & 0xffffu));
    }
    wave_fence();
#pragma unroll
    for (int ks = 0; ks < 2; ++ks) {
      Pa[ks] = as_s8(*(const uint4*)(scwu + qc * 136 + ks * 32 + g * 8));
      if (qi >= 8) Pa[ks] = s8zero();
    }
    mm8acc_lds(buf_s[s % 3], Pa, qi, g, Of);
  }

  // --- stages 21..23: win PV ---
#pragma unroll
  for (int wi = 0; wi < 3; ++wi) {
    const int s = 21 + wi;
    if (wi == 0) {
      dma_bar2();
      stage_dma(V16b + (size_t)wb2 * 2048, buf_s[(s + 2) % 3], w, lane); // tile 23
    } else if (wi == 1) {
      dma_bar2();
    } else {
      dma_bar0();   // drain: last tile must be fully landed
    }
#pragma unroll
    for (int j = 0; j < 8; ++j) {
      const unsigned uu = Lwp[j][wi >> 1];
      scwu[j * 136 + lane] = (unsigned short)((wi & 1) ? (uu >> 16) : (uu & 0xffffu));
    }
    wave_fence();
#pragma unroll
    for (int ks = 0; ks < 2; ++ks) {
      Pa[ks] = as_s8(*(const uint4*)(scwu + qc * 136 + ks * 32 + g * 8));
      if (qi >= 8) Pa[ks] = s8zero();
    }
    mm8acc_lds(buf_s[s % 3], Pa, qi, g, Of);
  }

  // ---- epilogue: Of -> lane=dim, store (cmp+sel+win+global)/3 ----
  float ofin[8];
  redist(Of, scw, lane, ofin);
#pragma unroll
  for (int j = 0; j < 8; ++j)
    outg[base + (size_t)(q0 + j) * DD + lane] = ofin[j] * (1.f / 3.f);
}

// ---------------------------------------------------------------------------
extern "C" void kernel_launch(void* const* d_in, const int* in_sizes, int n_in,
                              void* d_out, int out_size, void* d_ws, size_t ws_size,
                              hipStream_t stream) {
  (void)in_sizes; (void)n_in; (void)out_size; (void)ws_size;
  const float* q = (const float*)d_in[0];
  const float* k = (const float*)d_in[1];
  const float* v = (const float*)d_in[2];
  float* out = (float*)d_out;

  float*    wsf   = (float*)d_ws;
  float*    kblk  = wsf + OFF_KBLK;
  float*    vblk  = wsf + OFF_VBLK;
  int*      selI  = (int*)d_ws + OFF_SEL;
  unsigned* Kbar  = (unsigned*)d_ws + OFF_KBAR;
  unsigned* VbarT = (unsigned*)d_ws + OFF_VBART;
  unsigned* K16   = (unsigned*)d_ws + OFF_K16;
  unsigned* VT16  = (unsigned*)d_ws + OFF_VT16;

  dim3 g1(NBLK, 16);
  nsa_cvt<<<g1, 256, 0, stream>>>(k, v, kblk, vblk, K16, VT16);
  dim3 g2(NBLK, 16);
  nsa_group<<<g2, 64, 0, stream>>>(q, k, v, kblk, vblk, selI, Kbar, VbarT);
  dim3 g3(64, 16);
  nsa_main<<<g3, 256, 0, stream>>>(q, selI, Kbar, VbarT, K16, VT16, out);
}

// Round 16
// 94.503 us; speedup vs baseline: 1.0094x; 1.0094x over previous
//
#include <hip/hip_runtime.h>

// ---------------------------------------------------------------------------
// Native Sparse Attention (B=2, H=8, S=2048, D=64)
// == R15-PASSING (hardened fused-asm stage barriers) + ONE change:
// XCD-aware grid swizzle (retest now that the barrier-hoist race is fixed;
// R15's absmax improvement 0.0212->0.0156 confirmed the race diagnosis). ==
// Prep: nsa_cvt builds bf16 PRE-SWIZZLED 8KB tiles K16[bh][blk][tok][dim],
// VT16[bh][blk][dim][tok] (+ exact f32 block means); nsa_group (64 thr,
// serial, known-good) does exact fp32 factorized top-8 per 64-query group
// + K̄/V̄T bf16 tiles (k0/v0 folded). Main: block = 32 queries (4 waves x
// 8q); 1D grid of 1024, XCD i owns bh pair {2i,2i+1} -> ~1MB tile set
// L2-resident per XCD. 24 stages; ring-3 LDS staging via global_load_lds;
// counted vmcnt(2) per stage fused WITH s_barrier in one opaque asm blob
// (vmcnt(0) only at the last stage). Wave reductions: 4 valid DPP hops
// (intra-16) + 2 shfl_xor (cross-row).
// ---------------------------------------------------------------------------

constexpr int SS   = 2048;
constexpr int DD   = 64;
constexpr int NBLK = 32;
constexpr int BS   = 64;
constexpr int SNB  = 8;
constexpr int KKEEP = 256;
constexpr float SCALE  = 0.125f;
constexpr float NEGINF = -1e30f;

#define DEV __device__ __forceinline__

typedef __attribute__((ext_vector_type(8))) short s8_t;   // 8 x bf16
typedef __attribute__((ext_vector_type(4))) float f4_t;   // MFMA C/D frag

union S8U { uint4 u; s8_t s; };

DEV s8_t as_s8(uint4 u) { S8U x; x.u = u; return x.s; }
DEV s8_t s8zero() { uint4 z = {0, 0, 0, 0}; return as_s8(z); }

DEV float readlane_f(float x, int l) {
  return __int_as_float(__builtin_amdgcn_readlane(__float_as_int(x), l));
}
template <int CTRL>
DEV float dpp_mv(float x, float old) {
  return __int_as_float(__builtin_amdgcn_update_dpp(
      __float_as_int(old), __float_as_int(x), CTRL, 0xf, 0xf, false));
}
// wave64 reductions: intra-16 via VALID CDNA DPP controls, cross-row shfl.
DEV float wave_max(float x) {
  x = fmaxf(x, dpp_mv<0xB1>(x, x));
  x = fmaxf(x, dpp_mv<0x4E>(x, x));
  x = fmaxf(x, dpp_mv<0x141>(x, x));
  x = fmaxf(x, dpp_mv<0x140>(x, x));
  x = fmaxf(x, __shfl_xor(x, 16, 64));
  x = fmaxf(x, __shfl_xor(x, 32, 64));
  return x;
}
DEV float wave_sum(float x) {
  x += dpp_mv<0xB1>(x, 0.f);
  x += dpp_mv<0x4E>(x, 0.f);
  x += dpp_mv<0x141>(x, 0.f);
  x += dpp_mv<0x140>(x, 0.f);
  x += __shfl_xor(x, 16, 64);
  x += __shfl_xor(x, 32, 64);
  return x;
}
DEV unsigned cvt_pk(float lo, float hi) {
  unsigned d;
  asm("v_cvt_pk_bf16_f32 %0, %1, %2" : "=v"(d) : "v"(lo), "v"(hi));
  return d;
}
DEV f4_t mfma16(s8_t a, s8_t b, f4_t c) {
  return __builtin_amdgcn_mfma_f32_16x16x32_bf16(a, b, c, 0, 0, 0);
}
DEV void wave_fence() {
  asm volatile("s_waitcnt lgkmcnt(0)" ::: "memory");
  __builtin_amdgcn_sched_barrier(0);
}
// HARDENED stage barriers: wait + s_barrier fused in ONE opaque volatile asm
// with "memory" clobber -> indivisible; no load can be hoisted across the
// barrier by IR passes or the machine scheduler. vmcnt(2) keeps the next
// tile's 2 DMAs in flight; vmcnt(0) only at the final stage.
DEV void dma_bar2() {
  asm volatile("s_waitcnt vmcnt(2) lgkmcnt(0)\n\ts_barrier" ::: "memory");
  __builtin_amdgcn_sched_barrier(0);
}
DEV void dma_bar0() {
  asm volatile("s_waitcnt vmcnt(0) lgkmcnt(0)\n\ts_barrier" ::: "memory");
  __builtin_amdgcn_sched_barrier(0);
}

// swizzled uint index within an 8KB tile: row 0..63, chunk 0..7 (16B chunks)
DEV int swz(int row, int chunk) { return row * 32 + (((chunk) ^ (row & 7)) << 2); }

typedef __attribute__((address_space(1))) const unsigned GU;
typedef __attribute__((address_space(3))) unsigned LU;
// stage one 8KB tile: 4 waves x 2 instr x 64 lanes x 16B (linear copy)
DEV void stage_dma(const unsigned* tile, unsigned* lbuf, int w, int lane) {
#pragma unroll
  for (int j = 0; j < 2; ++j) {
    const unsigned* src = tile + ((w * 2 + j) * 64 + lane) * 4;
    __builtin_amdgcn_global_load_lds((GU*)src, (LU*)(lbuf + (w * 2 + j) * 256),
                                     16, 0, 0);
  }
}

// 8 MFMA from swizzled LDS tile (B rows = tokens for QK / dims for PV)
DEV void mm8_lds(const unsigned* buf, const s8_t A[2], int qi, int g, f4_t c[4]) {
#pragma unroll
  for (int t = 0; t < 4; ++t) {
    f4_t acc = {0.f, 0.f, 0.f, 0.f};
#pragma unroll
    for (int ks = 0; ks < 2; ++ks) {
      const s8_t B = as_s8(*(const uint4*)(buf + swz(t * 16 + qi, ks * 4 + g)));
      acc = mfma16(A[ks], B, acc);
    }
    c[t] = acc;
  }
}
DEV void mm8acc_lds(const unsigned* buf, const s8_t A[2], int qi, int g, f4_t Of[4]) {
#pragma unroll
  for (int ks = 0; ks < 2; ++ks) {
#pragma unroll
    for (int t = 0; t < 4; ++t) {
      const s8_t B = as_s8(*(const uint4*)(buf + swz(t * 16 + qi, ks * 4 + g)));
      Of[t] = mfma16(A[ks], B, Of[t]);
    }
  }
}

// redistribute C frags (q rows 0..7) -> per-lane raw[j], lane = col 0..63.
// col-major scratch [col 64][row 8]: 4x ds_write_b128 + 2x ds_read_b128.
DEV void redist(const f4_t c[4], float* scw, int lane, float raw[8]) {
  if (lane < 32) {
    const int g2 = lane >> 4, ci = lane & 15;
#pragma unroll
    for (int t = 0; t < 4; ++t)
      *(f4_t*)(scw + (t * 16 + ci) * 8 + g2 * 4) = c[t];
  }
  wave_fence();
  *(f4_t*)(raw)     = *(const f4_t*)(scw + lane * 8);
  *(f4_t*)(raw + 4) = *(const f4_t*)(scw + lane * 8 + 4);
}

// ---- ws layout (4-byte element offsets) ----
constexpr size_t OFF_KBLK  = 0;         // f32 16*32*64
constexpr size_t OFF_VBLK  = 32768;     // f32 16*32*64
constexpr size_t OFF_SEL   = 65536;     // int 16*32*8
constexpr size_t OFF_KBAR  = 69632;     // u32 16*2048 (swizzled tiles)
constexpr size_t OFF_VBART = 102400;    // u32 16*2048
constexpr size_t OFF_K16   = 135168;    // u32 16*32*2048
constexpr size_t OFF_VT16  = 1183744;   // u32 16*32*2048

// ---------------------------------------------------------------------------
// Prep 1: bf16 swizzled K/V tiles + exact f32 block means
__global__ __launch_bounds__(256) void nsa_cvt(
    const float* __restrict__ kg, const float* __restrict__ vg,
    float* __restrict__ kblk, float* __restrict__ vblk,
    unsigned* __restrict__ K16, unsigned* __restrict__ VT16) {
  const int blk = blockIdx.x, bh = blockIdx.y, tid = threadIdx.x;
  __shared__ float kl[64][65], vl[64][65];
  const size_t tb = ((size_t)bh * SS + (size_t)blk * BS) * DD;
  unsigned* Kt = K16 + ((size_t)bh * NBLK + blk) * 2048;
  unsigned* Vt = VT16 + ((size_t)bh * NBLK + blk) * 2048;
#pragma unroll
  for (int m = 0; m < 4; ++m) {
    const int f4i = tid + 256 * m;
    const int r = f4i >> 4, c = f4i & 15;
    const float4 kk = *(const float4*)(kg + tb + r * DD + c * 4);
    const float4 vv = *(const float4*)(vg + tb + r * DD + c * 4);
    kl[r][c * 4] = kk.x; kl[r][c * 4 + 1] = kk.y;
    kl[r][c * 4 + 2] = kk.z; kl[r][c * 4 + 3] = kk.w;
    vl[r][c * 4] = vv.x; vl[r][c * 4 + 1] = vv.y;
    vl[r][c * 4 + 2] = vv.z; vl[r][c * 4 + 3] = vv.w;
    const int a = r * 32 + (((c >> 1) ^ (r & 7)) << 2) + (c & 1) * 2;
    Kt[a]     = cvt_pk(kk.x, kk.y);
    Kt[a + 1] = cvt_pk(kk.z, kk.w);
  }
  __syncthreads();
  const int d = tid >> 2, cg = tid & 3;
#pragma unroll
  for (int cc = 0; cc < 2; ++cc) {
    const int c = cg * 2 + cc;
#pragma unroll
    for (int w4 = 0; w4 < 4; ++w4) {
      const int tp = c * 4 + w4;
      Vt[d * 32 + ((c ^ (d & 7)) << 2) + w4] = cvt_pk(vl[2 * tp][d], vl[2 * tp + 1][d]);
    }
  }
  if (tid < DD) {
    float sk = 0.f, sv = 0.f;
#pragma unroll 8
    for (int t = 0; t < BS; ++t) { sk += kl[t][tid]; sv += vl[t][tid]; }
    kblk[((size_t)bh * NBLK + blk) * DD + tid] = sk * (1.f / 64.f);
    vblk[((size_t)bh * NBLK + blk) * DD + tid] = sv * (1.f / 64.f);
  }
}

// ---------------------------------------------------------------------------
// Prep 2 (64 threads, serial — known-good): exact fp32 factorized block
// scores + top-8 per group; gp==0 builds Kbar16 / VbarT16 tiles.
__global__ __launch_bounds__(64) void nsa_group(
    const float* __restrict__ qg, const float* __restrict__ kg,
    const float* __restrict__ vg, const float* __restrict__ kblk,
    const float* __restrict__ vblk, int* __restrict__ selidx,
    unsigned* __restrict__ Kbar16, unsigned* __restrict__ VbarT16) {
  const int gp = blockIdx.x, bh = blockIdx.y, d = threadIdx.x;
  __shared__ float qb_s[64];
  __shared__ float sc_s[32];
  {
    const float* qp = qg + ((size_t)bh * SS + (size_t)gp * 64) * DD + d;
    float s = 0.f;
    for (int r = 0; r < 64; ++r) s += qp[r * DD];
    qb_s[d] = s;
  }
  __syncthreads();
  if (d < 32) {
    const float* kr = kblk + ((size_t)bh * NBLK + d) * DD;
    float p = 0.f;
    for (int dd = 0; dd < 64; ++dd) p = fmaf(qb_s[dd], kr[dd], p);
    sc_s[d] = (d <= gp) ? p : NEGINF;
  }
  __syncthreads();
  if (d == 0) {
    unsigned taken = 0u;
    for (int t = 0; t < SNB; ++t) {
      float best = -3.4e38f; int bi = 0;
      for (int n = 0; n < NBLK; ++n)
        if (!((taken >> n) & 1u) && sc_s[n] > best) { best = sc_s[n]; bi = n; }
      taken |= 1u << bi;
      selidx[((size_t)bh * NBLK + gp) * SNB + t] = bi;
    }
  }
  if (gp == 0) {
    unsigned* Kt = Kbar16 + (size_t)bh * 2048;
    unsigned* Vt = VbarT16 + (size_t)bh * 2048;
    if (d < 32) {
      for (int n = 0; n < 32; ++n)
        Kt[n * 32 + (((d >> 2) ^ (n & 7)) << 2) + (d & 3)] =
            cvt_pk(kblk[((size_t)bh * NBLK + n) * DD + 2 * d],
                   kblk[((size_t)bh * NBLK + n) * DD + 2 * d + 1]);
      Kt[32 * 32 + ((d >> 2) << 2) + (d & 3)] =
          cvt_pk(kg[(size_t)bh * SS * DD + 2 * d],
                 kg[(size_t)bh * SS * DD + 2 * d + 1]);
      for (int n = 33; n < 64; ++n)
        Kt[n * 32 + (((d >> 2) ^ (n & 7)) << 2) + (d & 3)] = 0u;
    }
    for (int tp = 0; tp < 32; ++tp) {
      unsigned u = 0u;
      if (tp < 16)
        u = cvt_pk(vblk[((size_t)bh * NBLK + 2 * tp) * DD + d],
                   vblk[((size_t)bh * NBLK + 2 * tp + 1) * DD + d]);
      else if (tp == 16)
        u = cvt_pk(vg[(size_t)bh * SS * DD + d], 0.f);
      Vt[d * 32 + (((tp >> 2) ^ (d & 7)) << 2) + (tp & 3)] = u;
    }
  }
}

// ---------------------------------------------------------------------------
// Main: 24 stages, ring-3 staging, counted vmcnt (fused barriers),
// XCD-swizzled 1D grid.
__global__ __launch_bounds__(256) void nsa_main(
    const float* __restrict__ qg, const int* __restrict__ selp,
    const unsigned* __restrict__ Kbar16, const unsigned* __restrict__ VbarT16,
    const unsigned* __restrict__ K16, const unsigned* __restrict__ VT16,
    float* __restrict__ outg) {
  const int tid  = threadIdx.x;
  const int w    = tid >> 6;
  const int lane = tid & 63;
  // XCD-aware swizzle (ONLY change vs R15): 1024 blocks; XCD i (lin%8) gets
  // contiguous virt range [i*128,(i+1)*128) = bh pair {2i,2i+1} -> tile
  // working set ~1MB/XCD (L2-resident). Bijective: 1024 % 8 == 0.
  const int lin  = blockIdx.x;
  const int virt = (lin & 7) * 128 + (lin >> 3);
  const int bh   = virt >> 6;
  const int xblk = virt & 63;
  const int qtile = xblk * 4 + w;           // 0..255 (8 queries each)
  const int gg    = xblk >> 1;              // 64-query group (block-uniform)
  const int q0    = qtile * 8;
  const size_t base = (size_t)bh * SS * DD;

  __shared__ __align__(16) unsigned buf_s[3][2048];  // 24 KB ring
  __shared__ __align__(16) float sc_f[4][576];       // per-wave scratch
  float* scw = sc_f[w];
  unsigned short* scwu = (unsigned short*)scw;
  const int qi = lane & 15, g = lane >> 4;
  const int qc = (qi < 8) ? qi : 0;

  const unsigned* K16b = K16 + (size_t)bh * NBLK * 2048;
  const unsigned* V16b = VT16 + (size_t)bh * NBLK * 2048;
  const int wb0 = (gg > 2) ? gg - 2 : 0;
  const int wb1 = (gg > 1) ? gg - 1 : 0;
  const int wb2 = gg;

  // ---- prologue: sel list, Q frags, first two tile DMAs ----
  int sel[SNB];
#pragma unroll
  for (int i = 0; i < SNB; ++i) sel[i] = selp[((size_t)bh * NBLK + gg) * SNB + i];
  s8_t qA[2];
  {
    const float* qr2 = qg + base + (size_t)(q0 + qc) * DD + g * 8;
    const float4 a0 = *(const float4*)(qr2);
    const float4 a1 = *(const float4*)(qr2 + 4);
    const float4 a2 = *(const float4*)(qr2 + 32);
    const float4 a3 = *(const float4*)(qr2 + 36);
    uint4 u0 = {cvt_pk(a0.x, a0.y), cvt_pk(a0.z, a0.w),
                cvt_pk(a1.x, a1.y), cvt_pk(a1.z, a1.w)};
    uint4 u1 = {cvt_pk(a2.x, a2.y), cvt_pk(a2.z, a2.w),
                cvt_pk(a3.x, a3.y), cvt_pk(a3.z, a3.w)};
    qA[0] = (qi < 8) ? as_s8(u0) : s8zero();
    qA[1] = (qi < 8) ? as_s8(u1) : s8zero();
  }
  // tiles 0 (K̄) and 1 (K sel[0])
  stage_dma(Kbar16 + (size_t)bh * 2048, buf_s[0], w, lane);
  stage_dma(K16b + (size_t)sel[0] * 2048, buf_s[1], w, lane);

  // ================= K phase =================
  unsigned cPp[4];
  float l192[8];
  // --- stage 0: K̄ (+k0 col 32) ---
  dma_bar2();
  stage_dma(K16b + (size_t)sel[1] * 2048, buf_s[2], w, lane);   // tile 2
  {
    f4_t c[4];
    mm8_lds(buf_s[0], qA, qi, g, c);
    float raw[8];
    redist(c, scw, lane, raw);
    float cPf[8];
#pragma unroll
    for (int j = 0; j < 8; ++j) {
      l192[j] = readlane_f(raw[j], 32) * SCALE;
      const bool valid = (lane < 32) && (lane <= gg);
      const float l = valid ? raw[j] * SCALE : NEGINF;
      const float m = wave_max(l);
      const float e = valid ? __expf(l - m) : 0.f;
      const float ss = wave_sum(e);
      cPf[j] = e / ss;
    }
#pragma unroll
    for (int ip = 0; ip < 4; ++ip) cPp[ip] = cvt_pk(cPf[2 * ip], cPf[2 * ip + 1]);
  }

  // --- stages 1..8: sel QK ---
  float L[8][SNB];
#pragma unroll
  for (int sbi = 0; sbi < SNB; ++sbi) {
    const int s = 1 + sbi;
    dma_bar2();
    const unsigned* nt = (sbi <= 5) ? (K16b + (size_t)sel[sbi + 2] * 2048)
                       : ((sbi == 6) ? (K16b + (size_t)wb0 * 2048)
                                     : (K16b + (size_t)wb1 * 2048));
    stage_dma(nt, buf_s[(s + 2) % 3], w, lane);
    f4_t c[4];
    mm8_lds(buf_s[s % 3], qA, qi, g, c);
    float raw[8];
    redist(c, scw, lane, raw);
    const int tok = sel[sbi] * BS + lane;
#pragma unroll
    for (int j = 0; j < 8; ++j)
      L[j][sbi] = (tok <= q0 + j) ? raw[j] * SCALE : NEGINF;
  }

  // ---- threshold (12-iter float-window) + sel softmax -> packed bf16 ----
  unsigned Lp[8][4];
#pragma unroll
  for (int j = 0; j < 8; ++j) {
    float m = L[j][0];
#pragma unroll
    for (int i = 1; i < SNB; ++i) m = fmaxf(m, L[j][i]);
    m = wave_max(m);
    float lo = m - 20.f, hi = m;
    int c0 = 0;
#pragma unroll
    for (int i = 0; i < SNB; ++i) c0 += __popcll(__ballot(L[j][i] >= lo));
    if (c0 >= KKEEP) {
      for (int it = 0; it < 12; ++it) {
        const float mid = 0.5f * (lo + hi);
        int cc = 0;
#pragma unroll
        for (int i = 0; i < SNB; ++i) cc += __popcll(__ballot(L[j][i] >= mid));
        if (cc >= KKEEP) lo = mid; else hi = mid;
      }
    }
    const float thr = lo;
    float s = 0.f;
#pragma unroll
    for (int i = 0; i < SNB; ++i) {
      const float e = (L[j][i] >= thr) ? __expf(L[j][i] - m) : 0.f;
      L[j][i] = e; s += e;
    }
    s = wave_sum(s);
    const float inv = 1.f / s;
#pragma unroll
    for (int ip = 0; ip < 4; ++ip)
      Lp[j][ip] = cvt_pk(L[j][2 * ip] * inv, L[j][2 * ip + 1] * inv);
  }

  // --- stages 9..11: win QK ---
  float Lw[8][3];
#pragma unroll
  for (int wi = 0; wi < 3; ++wi) {
    const int s = 9 + wi;
    const int wb = gg - 2 + wi;
    dma_bar2();
    const unsigned* nt = (wi == 0) ? (K16b + (size_t)wb2 * 2048)
                       : ((wi == 1) ? (VbarT16 + (size_t)bh * 2048)
                                    : (V16b + (size_t)sel[0] * 2048));
    stage_dma(nt, buf_s[(s + 2) % 3], w, lane);
    f4_t c[4];
    mm8_lds(buf_s[s % 3], qA, qi, g, c);
    float raw[8];
    redist(c, scw, lane, raw);
    const int tok = wb * BS + lane;
#pragma unroll
    for (int j = 0; j < 8; ++j) {
      const int pos = q0 + j;
      const bool valid = (wb >= 0) && (tok <= pos) && ((pos - tok < 128) || (tok == 0));
      Lw[j][wi] = valid ? raw[j] * SCALE : NEGINF;
    }
  }

  // ---- win softmax ----
  unsigned Lwp[8][2];
  float p192[8];
#pragma unroll
  for (int j = 0; j < 8; ++j) {
    const float l1 = (gg >= 3) ? l192[j] : NEGINF;
    float m = fmaxf(fmaxf(Lw[j][0], Lw[j][1]), Lw[j][2]);
    m = wave_max(m);
    m = fmaxf(m, l1);
    const float e0 = __expf(Lw[j][0] - m);
    const float e1 = __expf(Lw[j][1] - m);
    const float e2 = __expf(Lw[j][2] - m);
    float s = wave_sum(e0 + e1 + e2);
    const float e192 = (gg >= 3) ? __expf(l1 - m) : 0.f;
    s += e192;
    const float inv = 1.f / s;
    Lwp[j][0] = cvt_pk(e0 * inv, e1 * inv);
    Lwp[j][1] = cvt_pk(e2 * inv, 0.f);
    p192[j] = e192 * inv;
  }

  // ================= V phase =================
  f4_t Of[4];
#pragma unroll
  for (int t = 0; t < 4; ++t) Of[t] = (f4_t){0.f, 0.f, 0.f, 0.f};
  s8_t Pa[2];

  // --- stage 12: V̄ (cmp PV + global token at tok 32) ---
  dma_bar2();
  stage_dma(V16b + (size_t)sel[1] * 2048, buf_s[(12 + 2) % 3], w, lane); // tile 14
#pragma unroll
  for (int j = 0; j < 8; ++j) {
    const unsigned uu = cPp[j >> 1];
    unsigned short pv = (unsigned short)((j & 1) ? (uu >> 16) : (uu & 0xffffu));
    if (lane == 32) pv = (unsigned short)(cvt_pk(p192[j], 0.f) & 0xffffu);
    else if (lane > 32) pv = 0;
    scwu[j * 136 + lane] = pv;
  }
  wave_fence();
#pragma unroll
  for (int ks = 0; ks < 2; ++ks) {
    Pa[ks] = as_s8(*(const uint4*)(scwu + qc * 136 + ks * 32 + g * 8));
    if (qi >= 8) Pa[ks] = s8zero();
  }
  mm8acc_lds(buf_s[12 % 3], Pa, qi, g, Of);

  // --- stages 13..20: sel PV ---
#pragma unroll
  for (int sbi = 0; sbi < SNB; ++sbi) {
    const int s = 13 + sbi;
    dma_bar2();
    const unsigned* nt = (sbi <= 5) ? (V16b + (size_t)sel[sbi + 2] * 2048)
                       : ((sbi == 6) ? (V16b + (size_t)wb0 * 2048)
                                     : (V16b + (size_t)wb1 * 2048));
    stage_dma(nt, buf_s[(s + 2) % 3], w, lane);
#pragma unroll
    for (int j = 0; j < 8; ++j) {
      const unsigned uu = Lp[j][sbi >> 1];
      scwu[j * 136 + lane] = (unsigned short)((sbi & 1) ? (uu >> 16) : (uu & 0xffffu));
    }
    wave_fence();
#pragma unroll
    for (int ks = 0; ks < 2; ++ks) {
      Pa[ks] = as_s8(*(const uint4*)(scwu + qc * 136 + ks * 32 + g * 8));
      if (qi >= 8) Pa[ks] = s8zero();
    }
    mm8acc_lds(buf_s[s % 3], Pa, qi, g, Of);
  }

  // --- stages 21..23: win PV ---
#pragma unroll
  for (int wi = 0; wi < 3; ++wi) {
    const int s = 21 + wi;
    if (wi == 0) {
      dma_bar2();
      stage_dma(V16b + (size_t)wb2 * 2048, buf_s[(s + 2) % 3], w, lane); // tile 23
    } else if (wi == 1) {
      dma_bar2();
    } else {
      dma_bar0();   // drain: last tile must be fully landed
    }
#pragma unroll
    for (int j = 0; j < 8; ++j) {
      const unsigned uu = Lwp[j][wi >> 1];
      scwu[j * 136 + lane] = (unsigned short)((wi & 1) ? (uu >> 16) : (uu & 0xffffu));
    }
    wave_fence();
#pragma unroll
    for (int ks = 0; ks < 2; ++ks) {
      Pa[ks] = as_s8(*(const uint4*)(scwu + qc * 136 + ks * 32 + g * 8));
      if (qi >= 8) Pa[ks] = s8zero();
    }
    mm8acc_lds(buf_s[s % 3], Pa, qi, g, Of);
  }

  // ---- epilogue: Of -> lane=dim, store (cmp+sel+win+global)/3 ----
  float ofin[8];
  redist(Of, scw, lane, ofin);
#pragma unroll
  for (int j = 0; j < 8; ++j)
    outg[base + (size_t)(q0 + j) * DD + lane] = ofin[j] * (1.f / 3.f);
}

// ---------------------------------------------------------------------------
extern "C" void kernel_launch(void* const* d_in, const int* in_sizes, int n_in,
                              void* d_out, int out_size, void* d_ws, size_t ws_size,
                              hipStream_t stream) {
  (void)in_sizes; (void)n_in; (void)out_size; (void)ws_size;
  const float* q = (const float*)d_in[0];
  const float* k = (const float*)d_in[1];
  const float* v = (const float*)d_in[2];
  float* out = (float*)d_out;

  float*    wsf   = (float*)d_ws;
  float*    kblk  = wsf + OFF_KBLK;
  float*    vblk  = wsf + OFF_VBLK;
  int*      selI  = (int*)d_ws + OFF_SEL;
  unsigned* Kbar  = (unsigned*)d_ws + OFF_KBAR;
  unsigned* VbarT = (unsigned*)d_ws + OFF_VBART;
  unsigned* K16   = (unsigned*)d_ws + OFF_K16;
  unsigned* VT16  = (unsigned*)d_ws + OFF_VT16;

  dim3 g1(NBLK, 16);
  nsa_cvt<<<g1, 256, 0, stream>>>(k, v, kblk, vblk, K16, VT16);
  dim3 g2(NBLK, 16);
  nsa_group<<<g2, 64, 0, stream>>>(q, k, v, kblk, vblk, selI, Kbar, VbarT);
  nsa_main<<<dim3(1024), 256, 0, stream>>>(q, selI, Kbar, VbarT, K16, VT16, out);
}

// Round 17
// 94.317 us; speedup vs baseline: 1.0113x; 1.0020x over previous
//
#include <hip/hip_runtime.h>

// ---------------------------------------------------------------------------
// Native Sparse Attention (B=2, H=8, S=2048, D=64)
// == R16-PASSING (hardened fused-asm barriers + XCD swizzle) + prep-path
// restructure: selection moved into nsa_main's prologue (R7-style per-wave
// redundant factorized top-8, proven); nsa_group replaced by tiny parallel
// nsa_bar tile builder (grid 16 x 256 thr). ==
// Prep: nsa_cvt builds bf16 PRE-SWIZZLED 8KB tiles K16[bh][blk][tok][dim],
// VT16[bh][blk][dim][tok] + exact f32 block means; nsa_bar builds K̄/V̄T
// bf16 tiles (k0/v0 folded). Main: block = 32 queries (4 waves x 8q);
// 1D grid of 1024, XCD i owns bh pair {2i,2i+1} (tiles L2-resident).
// 24 stages; ring-3 LDS staging via global_load_lds; counted vmcnt(2)
// fused WITH s_barrier in one opaque asm blob (vmcnt(0) only last stage).
// Wave reductions: 4 valid DPP hops (intra-16) + 2 shfl_xor (cross-row).
// ---------------------------------------------------------------------------

constexpr int SS   = 2048;
constexpr int DD   = 64;
constexpr int NBLK = 32;
constexpr int BS   = 64;
constexpr int SNB  = 8;
constexpr int KKEEP = 256;
constexpr float SCALE  = 0.125f;
constexpr float NEGINF = -1e30f;

#define DEV __device__ __forceinline__

typedef __attribute__((ext_vector_type(8))) short s8_t;   // 8 x bf16
typedef __attribute__((ext_vector_type(4))) float f4_t;   // MFMA C/D frag

union S8U { uint4 u; s8_t s; };

DEV s8_t as_s8(uint4 u) { S8U x; x.u = u; return x.s; }
DEV s8_t s8zero() { uint4 z = {0, 0, 0, 0}; return as_s8(z); }

DEV float readlane_f(float x, int l) {
  return __int_as_float(__builtin_amdgcn_readlane(__float_as_int(x), l));
}
template <int CTRL>
DEV float dpp_mv(float x, float old) {
  return __int_as_float(__builtin_amdgcn_update_dpp(
      __float_as_int(old), __float_as_int(x), CTRL, 0xf, 0xf, false));
}
// wave64 reductions: intra-16 via VALID CDNA DPP controls, cross-row shfl.
DEV float wave_max(float x) {
  x = fmaxf(x, dpp_mv<0xB1>(x, x));
  x = fmaxf(x, dpp_mv<0x4E>(x, x));
  x = fmaxf(x, dpp_mv<0x141>(x, x));
  x = fmaxf(x, dpp_mv<0x140>(x, x));
  x = fmaxf(x, __shfl_xor(x, 16, 64));
  x = fmaxf(x, __shfl_xor(x, 32, 64));
  return x;
}
DEV float wave_sum(float x) {
  x += dpp_mv<0xB1>(x, 0.f);
  x += dpp_mv<0x4E>(x, 0.f);
  x += dpp_mv<0x141>(x, 0.f);
  x += dpp_mv<0x140>(x, 0.f);
  x += __shfl_xor(x, 16, 64);
  x += __shfl_xor(x, 32, 64);
  return x;
}
DEV unsigned cvt_pk(float lo, float hi) {
  unsigned d;
  asm("v_cvt_pk_bf16_f32 %0, %1, %2" : "=v"(d) : "v"(lo), "v"(hi));
  return d;
}
DEV f4_t mfma16(s8_t a, s8_t b, f4_t c) {
  return __builtin_amdgcn_mfma_f32_16x16x32_bf16(a, b, c, 0, 0, 0);
}
DEV void wave_fence() {
  asm volatile("s_waitcnt lgkmcnt(0)" ::: "memory");
  __builtin_amdgcn_sched_barrier(0);
}
// HARDENED stage barriers: wait + s_barrier fused in ONE opaque volatile asm
// with "memory" clobber -> indivisible; no load hoisted across the barrier.
DEV void dma_bar2() {
  asm volatile("s_waitcnt vmcnt(2) lgkmcnt(0)\n\ts_barrier" ::: "memory");
  __builtin_amdgcn_sched_barrier(0);
}
DEV void dma_bar0() {
  asm volatile("s_waitcnt vmcnt(0) lgkmcnt(0)\n\ts_barrier" ::: "memory");
  __builtin_amdgcn_sched_barrier(0);
}

// swizzled uint index within an 8KB tile: row 0..63, chunk 0..7 (16B chunks)
DEV int swz(int row, int chunk) { return row * 32 + (((chunk) ^ (row & 7)) << 2); }

typedef __attribute__((address_space(1))) const unsigned GU;
typedef __attribute__((address_space(3))) unsigned LU;
// stage one 8KB tile: 4 waves x 2 instr x 64 lanes x 16B (linear copy)
DEV void stage_dma(const unsigned* tile, unsigned* lbuf, int w, int lane) {
#pragma unroll
  for (int j = 0; j < 2; ++j) {
    const unsigned* src = tile + ((w * 2 + j) * 64 + lane) * 4;
    __builtin_amdgcn_global_load_lds((GU*)src, (LU*)(lbuf + (w * 2 + j) * 256),
                                     16, 0, 0);
  }
}

// 8 MFMA from swizzled LDS tile (B rows = tokens for QK / dims for PV)
DEV void mm8_lds(const unsigned* buf, const s8_t A[2], int qi, int g, f4_t c[4]) {
#pragma unroll
  for (int t = 0; t < 4; ++t) {
    f4_t acc = {0.f, 0.f, 0.f, 0.f};
#pragma unroll
    for (int ks = 0; ks < 2; ++ks) {
      const s8_t B = as_s8(*(const uint4*)(buf + swz(t * 16 + qi, ks * 4 + g)));
      acc = mfma16(A[ks], B, acc);
    }
    c[t] = acc;
  }
}
DEV void mm8acc_lds(const unsigned* buf, const s8_t A[2], int qi, int g, f4_t Of[4]) {
#pragma unroll
  for (int ks = 0; ks < 2; ++ks) {
#pragma unroll
    for (int t = 0; t < 4; ++t) {
      const s8_t B = as_s8(*(const uint4*)(buf + swz(t * 16 + qi, ks * 4 + g)));
      Of[t] = mfma16(A[ks], B, Of[t]);
    }
  }
}

// redistribute C frags (q rows 0..7) -> per-lane raw[j], lane = col 0..63.
DEV void redist(const f4_t c[4], float* scw, int lane, float raw[8]) {
  if (lane < 32) {
    const int g2 = lane >> 4, ci = lane & 15;
#pragma unroll
    for (int t = 0; t < 4; ++t)
      *(f4_t*)(scw + (t * 16 + ci) * 8 + g2 * 4) = c[t];
  }
  wave_fence();
  *(f4_t*)(raw)     = *(const f4_t*)(scw + lane * 8);
  *(f4_t*)(raw + 4) = *(const f4_t*)(scw + lane * 8 + 4);
}

// ---- ws layout (4-byte element offsets) ----
constexpr size_t OFF_KBLK  = 0;         // f32 16*32*64
constexpr size_t OFF_VBLK  = 32768;     // f32 16*32*64
constexpr size_t OFF_SEL   = 65536;     // (unused now)
constexpr size_t OFF_KBAR  = 69632;     // u32 16*2048 (swizzled tiles)
constexpr size_t OFF_VBART = 102400;    // u32 16*2048
constexpr size_t OFF_K16   = 135168;    // u32 16*32*2048
constexpr size_t OFF_VT16  = 1183744;   // u32 16*32*2048

// ---------------------------------------------------------------------------
// Prep 1: bf16 swizzled K/V tiles + exact f32 block means
__global__ __launch_bounds__(256) void nsa_cvt(
    const float* __restrict__ kg, const float* __restrict__ vg,
    float* __restrict__ kblk, float* __restrict__ vblk,
    unsigned* __restrict__ K16, unsigned* __restrict__ VT16) {
  const int blk = blockIdx.x, bh = blockIdx.y, tid = threadIdx.x;
  __shared__ float kl[64][65], vl[64][65];
  const size_t tb = ((size_t)bh * SS + (size_t)blk * BS) * DD;
  unsigned* Kt = K16 + ((size_t)bh * NBLK + blk) * 2048;
  unsigned* Vt = VT16 + ((size_t)bh * NBLK + blk) * 2048;
#pragma unroll
  for (int m = 0; m < 4; ++m) {
    const int f4i = tid + 256 * m;
    const int r = f4i >> 4, c = f4i & 15;
    const float4 kk = *(const float4*)(kg + tb + r * DD + c * 4);
    const float4 vv = *(const float4*)(vg + tb + r * DD + c * 4);
    kl[r][c * 4] = kk.x; kl[r][c * 4 + 1] = kk.y;
    kl[r][c * 4 + 2] = kk.z; kl[r][c * 4 + 3] = kk.w;
    vl[r][c * 4] = vv.x; vl[r][c * 4 + 1] = vv.y;
    vl[r][c * 4 + 2] = vv.z; vl[r][c * 4 + 3] = vv.w;
    const int a = r * 32 + (((c >> 1) ^ (r & 7)) << 2) + (c & 1) * 2;
    Kt[a]     = cvt_pk(kk.x, kk.y);
    Kt[a + 1] = cvt_pk(kk.z, kk.w);
  }
  __syncthreads();
  const int d = tid >> 2, cg = tid & 3;
#pragma unroll
  for (int cc = 0; cc < 2; ++cc) {
    const int c = cg * 2 + cc;
#pragma unroll
    for (int w4 = 0; w4 < 4; ++w4) {
      const int tp = c * 4 + w4;
      Vt[d * 32 + ((c ^ (d & 7)) << 2) + w4] = cvt_pk(vl[2 * tp][d], vl[2 * tp + 1][d]);
    }
  }
  if (tid < DD) {
    float sk = 0.f, sv = 0.f;
#pragma unroll 8
    for (int t = 0; t < BS; ++t) { sk += kl[t][tid]; sv += vl[t][tid]; }
    kblk[((size_t)bh * NBLK + blk) * DD + tid] = sk * (1.f / 64.f);
    vblk[((size_t)bh * NBLK + blk) * DD + tid] = sv * (1.f / 64.f);
  }
}

// ---------------------------------------------------------------------------
// Prep 2 (tiny, parallel): K̄/V̄T swizzled tiles per bh (k0/v0 folded).
__global__ __launch_bounds__(256) void nsa_bar(
    const float* __restrict__ kg, const float* __restrict__ vg,
    const float* __restrict__ kblk, const float* __restrict__ vblk,
    unsigned* __restrict__ Kbar16, unsigned* __restrict__ VbarT16) {
  const int bh = blockIdx.x, tid = threadIdx.x;
  unsigned* Kt = Kbar16 + (size_t)bh * 2048;
  unsigned* Vt = VbarT16 + (size_t)bh * 2048;
  for (int i = tid; i < 2048; i += 256) {
    const int n = i >> 5, c = i & 31;
    unsigned u = 0u;
    if (n < 32)
      u = cvt_pk(kblk[((size_t)bh * NBLK + n) * DD + 2 * c],
                 kblk[((size_t)bh * NBLK + n) * DD + 2 * c + 1]);
    else if (n == 32)
      u = cvt_pk(kg[(size_t)bh * SS * DD + 2 * c],
                 kg[(size_t)bh * SS * DD + 2 * c + 1]);
    Kt[n * 32 + (((c >> 2) ^ (n & 7)) << 2) + (c & 3)] = u;
  }
  for (int i = tid; i < 2048; i += 256) {
    const int d = i >> 5, tp = i & 31;
    unsigned u = 0u;
    if (tp < 16)
      u = cvt_pk(vblk[((size_t)bh * NBLK + 2 * tp) * DD + d],
                 vblk[((size_t)bh * NBLK + 2 * tp + 1) * DD + d]);
    else if (tp == 16)
      u = cvt_pk(vg[(size_t)bh * SS * DD + d], 0.f);
    Vt[d * 32 + (((tp >> 2) ^ (d & 7)) << 2) + (tp & 3)] = u;
  }
}

// ---------------------------------------------------------------------------
// Main: in-block selection prologue + 24 stages, ring-3 staging, counted
// vmcnt (fused barriers), XCD-swizzled 1D grid.
__global__ __launch_bounds__(256) void nsa_main(
    const float* __restrict__ qg, const float* __restrict__ kblk,
    const unsigned* __restrict__ Kbar16, const unsigned* __restrict__ VbarT16,
    const unsigned* __restrict__ K16, const unsigned* __restrict__ VT16,
    float* __restrict__ outg) {
  const int tid  = threadIdx.x;
  const int w    = tid >> 6;
  const int lane = tid & 63;
  // XCD-aware swizzle: XCD i (lin%8) owns bh pair {2i,2i+1}. Bijective.
  const int lin  = blockIdx.x;
  const int virt = (lin & 7) * 128 + (lin >> 3);
  const int bh   = virt >> 6;
  const int xblk = virt & 63;
  const int qtile = xblk * 4 + w;           // 0..255 (8 queries each)
  const int gg    = xblk >> 1;              // 64-query group (block-uniform)
  const int q0    = qtile * 8;
  const size_t base = (size_t)bh * SS * DD;

  __shared__ __align__(16) unsigned buf_s[3][2048];  // 24 KB ring
  __shared__ __align__(16) float sc_f[4][576];       // per-wave scratch
  __shared__ float partial_s[4][64];                 // group Q-sum partials
  float* scw = sc_f[w];
  unsigned short* scwu = (unsigned short*)scw;
  const int qi = lane & 15, g = lane >> 4;
  const int qc = (qi < 8) ? qi : 0;

  const unsigned* K16b = K16 + (size_t)bh * NBLK * 2048;
  const unsigned* V16b = VT16 + (size_t)bh * NBLK * 2048;
  const int wb0 = (gg > 2) ? gg - 2 : 0;
  const int wb1 = (gg > 1) ? gg - 1 : 0;
  const int wb2 = gg;

  // ---- prologue: group Q partials, qA frags ----
  {
    const float* qp = qg + base + (size_t)(gg * 64 + w * 16) * DD + lane;
    float qs = 0.f;
#pragma unroll 4
    for (int r = 0; r < 16; ++r) qs += qp[r * DD];
    partial_s[w][lane] = qs;
  }
  s8_t qA[2];
  {
    const float* qr2 = qg + base + (size_t)(q0 + qc) * DD + g * 8;
    const float4 a0 = *(const float4*)(qr2);
    const float4 a1 = *(const float4*)(qr2 + 4);
    const float4 a2 = *(const float4*)(qr2 + 32);
    const float4 a3 = *(const float4*)(qr2 + 36);
    uint4 u0 = {cvt_pk(a0.x, a0.y), cvt_pk(a0.z, a0.w),
                cvt_pk(a1.x, a1.y), cvt_pk(a1.z, a1.w)};
    uint4 u1 = {cvt_pk(a2.x, a2.y), cvt_pk(a2.z, a2.w),
                cvt_pk(a3.x, a3.y), cvt_pk(a3.z, a3.w)};
    qA[0] = (qi < 8) ? as_s8(u0) : s8zero();
    qA[1] = (qi < 8) ? as_s8(u1) : s8zero();
  }
  __syncthreads();   // publish partial_s (no DMAs in flight yet)

  // ---- per-wave redundant exact factorized block scores + top-8 ----
  int sel[SNB];
  {
    float qm = 0.f;
#pragma unroll
    for (int ww = 0; ww < 4; ++ww) qm += partial_s[ww][lane];
    scw[lane] = qm;   // unnormalized group mean (positive scale: rank-safe)
    wave_fence();
    const int n2 = lane & 31, half = lane >> 5;
    const float* krow = kblk + ((size_t)bh * NBLK + n2) * DD + half * 32;
    float p = 0.f;
#pragma unroll
    for (int dd = 0; dd < 32; ++dd) p = fmaf(scw[half * 32 + dd], krow[dd], p);
    p += __shfl_xor(p, 32, 64);
    float s = (lane < 32) ? ((n2 <= gg) ? p : NEGINF) : -3.4e38f;
    const int bi = lane;
    for (int t = 0; t < SNB; ++t) {
      float bs = s; int bb = bi;
#pragma unroll
      for (int o = 32; o > 0; o >>= 1) {
        const float os = __shfl_xor(bs, o, 64);
        const int   ob = __shfl_xor(bb, o, 64);
        if (os > bs || (os == bs && ob < bb)) { bs = os; bb = ob; }
      }
      sel[t] = bb;
      if (bi == bb) s = -3.4e38f;
    }
  }

  // tiles 0 (K̄) and 1 (K sel[0])
  stage_dma(Kbar16 + (size_t)bh * 2048, buf_s[0], w, lane);
  stage_dma(K16b + (size_t)sel[0] * 2048, buf_s[1], w, lane);

  // ================= K phase =================
  unsigned cPp[4];
  float l192[8];
  // --- stage 0: K̄ (+k0 col 32) ---
  dma_bar2();
  stage_dma(K16b + (size_t)sel[1] * 2048, buf_s[2], w, lane);   // tile 2
  {
    f4_t c[4];
    mm8_lds(buf_s[0], qA, qi, g, c);
    float raw[8];
    redist(c, scw, lane, raw);
    float cPf[8];
#pragma unroll
    for (int j = 0; j < 8; ++j) {
      l192[j] = readlane_f(raw[j], 32) * SCALE;
      const bool valid = (lane < 32) && (lane <= gg);
      const float l = valid ? raw[j] * SCALE : NEGINF;
      const float m = wave_max(l);
      const float e = valid ? __expf(l - m) : 0.f;
      const float ss = wave_sum(e);
      cPf[j] = e / ss;
    }
#pragma unroll
    for (int ip = 0; ip < 4; ++ip) cPp[ip] = cvt_pk(cPf[2 * ip], cPf[2 * ip + 1]);
  }

  // --- stages 1..8: sel QK ---
  float L[8][SNB];
#pragma unroll
  for (int sbi = 0; sbi < SNB; ++sbi) {
    const int s = 1 + sbi;
    dma_bar2();
    const unsigned* nt = (sbi <= 5) ? (K16b + (size_t)sel[sbi + 2] * 2048)
                       : ((sbi == 6) ? (K16b + (size_t)wb0 * 2048)
                                     : (K16b + (size_t)wb1 * 2048));
    stage_dma(nt, buf_s[(s + 2) % 3], w, lane);
    f4_t c[4];
    mm8_lds(buf_s[s % 3], qA, qi, g, c);
    float raw[8];
    redist(c, scw, lane, raw);
    const int tok = sel[sbi] * BS + lane;
#pragma unroll
    for (int j = 0; j < 8; ++j)
      L[j][sbi] = (tok <= q0 + j) ? raw[j] * SCALE : NEGINF;
  }

  // ---- threshold (12-iter float-window) + sel softmax -> packed bf16 ----
  unsigned Lp[8][4];
#pragma unroll
  for (int j = 0; j < 8; ++j) {
    float m = L[j][0];
#pragma unroll
    for (int i = 1; i < SNB; ++i) m = fmaxf(m, L[j][i]);
    m = wave_max(m);
    float lo = m - 20.f, hi = m;
    int c0 = 0;
#pragma unroll
    for (int i = 0; i < SNB; ++i) c0 += __popcll(__ballot(L[j][i] >= lo));
    if (c0 >= KKEEP) {
      for (int it = 0; it < 12; ++it) {
        const float mid = 0.5f * (lo + hi);
        int cc = 0;
#pragma unroll
        for (int i = 0; i < SNB; ++i) cc += __popcll(__ballot(L[j][i] >= mid));
        if (cc >= KKEEP) lo = mid; else hi = mid;
      }
    }
    const float thr = lo;
    float s = 0.f;
#pragma unroll
    for (int i = 0; i < SNB; ++i) {
      const float e = (L[j][i] >= thr) ? __expf(L[j][i] - m) : 0.f;
      L[j][i] = e; s += e;
    }
    s = wave_sum(s);
    const float inv = 1.f / s;
#pragma unroll
    for (int ip = 0; ip < 4; ++ip)
      Lp[j][ip] = cvt_pk(L[j][2 * ip] * inv, L[j][2 * ip + 1] * inv);
  }

  // --- stages 9..11: win QK ---
  float Lw[8][3];
#pragma unroll
  for (int wi = 0; wi < 3; ++wi) {
    const int s = 9 + wi;
    const int wb = gg - 2 + wi;
    dma_bar2();
    const unsigned* nt = (wi == 0) ? (K16b + (size_t)wb2 * 2048)
                       : ((wi == 1) ? (VbarT16 + (size_t)bh * 2048)
                                    : (V16b + (size_t)sel[0] * 2048));
    stage_dma(nt, buf_s[(s + 2) % 3], w, lane);
    f4_t c[4];
    mm8_lds(buf_s[s % 3], qA, qi, g, c);
    float raw[8];
    redist(c, scw, lane, raw);
    const int tok = wb * BS + lane;
#pragma unroll
    for (int j = 0; j < 8; ++j) {
      const int pos = q0 + j;
      const bool valid = (wb >= 0) && (tok <= pos) && ((pos - tok < 128) || (tok == 0));
      Lw[j][wi] = valid ? raw[j] * SCALE : NEGINF;
    }
  }

  // ---- win softmax ----
  unsigned Lwp[8][2];
  float p192[8];
#pragma unroll
  for (int j = 0; j < 8; ++j) {
    const float l1 = (gg >= 3) ? l192[j] : NEGINF;
    float m = fmaxf(fmaxf(Lw[j][0], Lw[j][1]), Lw[j][2]);
    m = wave_max(m);
    m = fmaxf(m, l1);
    const float e0 = __expf(Lw[j][0] - m);
    const float e1 = __expf(Lw[j][1] - m);
    const float e2 = __expf(Lw[j][2] - m);
    float s = wave_sum(e0 + e1 + e2);
    const float e192 = (gg >= 3) ? __expf(l1 - m) : 0.f;
    s += e192;
    const float inv = 1.f / s;
    Lwp[j][0] = cvt_pk(e0 * inv, e1 * inv);
    Lwp[j][1] = cvt_pk(e2 * inv, 0.f);
    p192[j] = e192 * inv;
  }

  // ================= V phase =================
  f4_t Of[4];
#pragma unroll
  for (int t = 0; t < 4; ++t) Of[t] = (f4_t){0.f, 0.f, 0.f, 0.f};
  s8_t Pa[2];

  // --- stage 12: V̄ (cmp PV + global token at tok 32) ---
  dma_bar2();
  stage_dma(V16b + (size_t)sel[1] * 2048, buf_s[(12 + 2) % 3], w, lane); // tile 14
#pragma unroll
  for (int j = 0; j < 8; ++j) {
    const unsigned uu = cPp[j >> 1];
    unsigned short pv = (unsigned short)((j & 1) ? (uu >> 16) : (uu & 0xffffu));
    if (lane == 32) pv = (unsigned short)(cvt_pk(p192[j], 0.f) & 0xffffu);
    else if (lane > 32) pv = 0;
    scwu[j * 136 + lane] = pv;
  }
  wave_fence();
#pragma unroll
  for (int ks = 0; ks < 2; ++ks) {
    Pa[ks] = as_s8(*(const uint4*)(scwu + qc * 136 + ks * 32 + g * 8));
    if (qi >= 8) Pa[ks] = s8zero();
  }
  mm8acc_lds(buf_s[12 % 3], Pa, qi, g, Of);

  // --- stages 13..20: sel PV ---
#pragma unroll
  for (int sbi = 0; sbi < SNB; ++sbi) {
    const int s = 13 + sbi;
    dma_bar2();
    const unsigned* nt = (sbi <= 5) ? (V16b + (size_t)sel[sbi + 2] * 2048)
                       : ((sbi == 6) ? (V16b + (size_t)wb0 * 2048)
                                     : (V16b + (size_t)wb1 * 2048));
    stage_dma(nt, buf_s[(s + 2) % 3], w, lane);
#pragma unroll
    for (int j = 0; j < 8; ++j) {
      const unsigned uu = Lp[j][sbi >> 1];
      scwu[j * 136 + lane] = (unsigned short)((sbi & 1) ? (uu >> 16) : (uu & 0xffffu));
    }
    wave_fence();
#pragma unroll
    for (int ks = 0; ks < 2; ++ks) {
      Pa[ks] = as_s8(*(const uint4*)(scwu + qc * 136 + ks * 32 + g * 8));
      if (qi >= 8) Pa[ks] = s8zero();
    }
    mm8acc_lds(buf_s[s % 3], Pa, qi, g, Of);
  }

  // --- stages 21..23: win PV ---
#pragma unroll
  for (int wi = 0; wi < 3; ++wi) {
    const int s = 21 + wi;
    if (wi == 0) {
      dma_bar2();
      stage_dma(V16b + (size_t)wb2 * 2048, buf_s[(s + 2) % 3], w, lane); // tile 23
    } else if (wi == 1) {
      dma_bar2();
    } else {
      dma_bar0();   // drain: last tile must be fully landed
    }
#pragma unroll
    for (int j = 0; j < 8; ++j) {
      const unsigned uu = Lwp[j][wi >> 1];
      scwu[j * 136 + lane] = (unsigned short)((wi & 1) ? (uu >> 16) : (uu & 0xffffu));
    }
    wave_fence();
#pragma unroll
    for (int ks = 0; ks < 2; ++ks) {
      Pa[ks] = as_s8(*(const uint4*)(scwu + qc * 136 + ks * 32 + g * 8));
      if (qi >= 8) Pa[ks] = s8zero();
    }
    mm8acc_lds(buf_s[s % 3], Pa, qi, g, Of);
  }

  // ---- epilogue: Of -> lane=dim, store (cmp+sel+win+global)/3 ----
  float ofin[8];
  redist(Of, scw, lane, ofin);
#pragma unroll
  for (int j = 0; j < 8; ++j)
    outg[base + (size_t)(q0 + j) * DD + lane] = ofin[j] * (1.f / 3.f);
}

// ---------------------------------------------------------------------------
extern "C" void kernel_launch(void* const* d_in, const int* in_sizes, int n_in,
                              void* d_out, int out_size, void* d_ws, size_t ws_size,
                              hipStream_t stream) {
  (void)in_sizes; (void)n_in; (void)out_size; (void)ws_size;
  const float* q = (const float*)d_in[0];
  const float* k = (const float*)d_in[1];
  const float* v = (const float*)d_in[2];
  float* out = (float*)d_out;

  float*    wsf   = (float*)d_ws;
  float*    kblk  = wsf + OFF_KBLK;
  float*    vblk  = wsf + OFF_VBLK;
  unsigned* Kbar  = (unsigned*)d_ws + OFF_KBAR;
  unsigned* VbarT = (unsigned*)d_ws + OFF_VBART;
  unsigned* K16   = (unsigned*)d_ws + OFF_K16;
  unsigned* VT16  = (unsigned*)d_ws + OFF_VT16;

  dim3 g1(NBLK, 16);
  nsa_cvt<<<g1, 256, 0, stream>>>(k, v, kblk, vblk, K16, VT16);
  nsa_bar<<<dim3(16), 256, 0, stream>>>(k, v, kblk, vblk, Kbar, VbarT);
  nsa_main<<<dim3(1024), 256, 0, stream>>>(q, kblk, Kbar, VbarT, K16, VT16, out);
}

// Round 18
// 90.981 us; speedup vs baseline: 1.0484x; 1.0367x over previous
//
#include <hip/hip_runtime.h>

// ---------------------------------------------------------------------------
// Native Sparse Attention (B=2, H=8, S=2048, D=64)
// == R16-PASSING main (selection via selp, hardened fused-asm barriers,
// XCD swizzle, ring-3 counted-vmcnt DMA staging) + fast parallel prep:
// nsa_cvt (bf16 swizzled tiles + means), nsa_bar (K̄/V̄T tiles, parallel),
// nsa_sel (selection-only, 256thr: R17's proven prologue extracted). ==
// ---------------------------------------------------------------------------

constexpr int SS   = 2048;
constexpr int DD   = 64;
constexpr int NBLK = 32;
constexpr int BS   = 64;
constexpr int SNB  = 8;
constexpr int KKEEP = 256;
constexpr float SCALE  = 0.125f;
constexpr float NEGINF = -1e30f;

#define DEV __device__ __forceinline__

typedef __attribute__((ext_vector_type(8))) short s8_t;   // 8 x bf16
typedef __attribute__((ext_vector_type(4))) float f4_t;   // MFMA C/D frag

union S8U { uint4 u; s8_t s; };

DEV s8_t as_s8(uint4 u) { S8U x; x.u = u; return x.s; }
DEV s8_t s8zero() { uint4 z = {0, 0, 0, 0}; return as_s8(z); }

DEV float readlane_f(float x, int l) {
  return __int_as_float(__builtin_amdgcn_readlane(__float_as_int(x), l));
}
template <int CTRL>
DEV float dpp_mv(float x, float old) {
  return __int_as_float(__builtin_amdgcn_update_dpp(
      __float_as_int(old), __float_as_int(x), CTRL, 0xf, 0xf, false));
}
// wave64 reductions: intra-16 via VALID CDNA DPP controls, cross-row shfl.
DEV float wave_max(float x) {
  x = fmaxf(x, dpp_mv<0xB1>(x, x));
  x = fmaxf(x, dpp_mv<0x4E>(x, x));
  x = fmaxf(x, dpp_mv<0x141>(x, x));
  x = fmaxf(x, dpp_mv<0x140>(x, x));
  x = fmaxf(x, __shfl_xor(x, 16, 64));
  x = fmaxf(x, __shfl_xor(x, 32, 64));
  return x;
}
DEV float wave_sum(float x) {
  x += dpp_mv<0xB1>(x, 0.f);
  x += dpp_mv<0x4E>(x, 0.f);
  x += dpp_mv<0x141>(x, 0.f);
  x += dpp_mv<0x140>(x, 0.f);
  x += __shfl_xor(x, 16, 64);
  x += __shfl_xor(x, 32, 64);
  return x;
}
DEV unsigned cvt_pk(float lo, float hi) {
  unsigned d;
  asm("v_cvt_pk_bf16_f32 %0, %1, %2" : "=v"(d) : "v"(lo), "v"(hi));
  return d;
}
DEV f4_t mfma16(s8_t a, s8_t b, f4_t c) {
  return __builtin_amdgcn_mfma_f32_16x16x32_bf16(a, b, c, 0, 0, 0);
}
DEV void wave_fence() {
  asm volatile("s_waitcnt lgkmcnt(0)" ::: "memory");
  __builtin_amdgcn_sched_barrier(0);
}
// HARDENED stage barriers: wait + s_barrier fused in ONE opaque volatile asm
// with "memory" clobber -> indivisible; no load hoisted across the barrier.
DEV void dma_bar2() {
  asm volatile("s_waitcnt vmcnt(2) lgkmcnt(0)\n\ts_barrier" ::: "memory");
  __builtin_amdgcn_sched_barrier(0);
}
DEV void dma_bar0() {
  asm volatile("s_waitcnt vmcnt(0) lgkmcnt(0)\n\ts_barrier" ::: "memory");
  __builtin_amdgcn_sched_barrier(0);
}

// swizzled uint index within an 8KB tile: row 0..63, chunk 0..7 (16B chunks)
DEV int swz(int row, int chunk) { return row * 32 + (((chunk) ^ (row & 7)) << 2); }

typedef __attribute__((address_space(1))) const unsigned GU;
typedef __attribute__((address_space(3))) unsigned LU;
// stage one 8KB tile: 4 waves x 2 instr x 64 lanes x 16B (linear copy)
DEV void stage_dma(const unsigned* tile, unsigned* lbuf, int w, int lane) {
#pragma unroll
  for (int j = 0; j < 2; ++j) {
    const unsigned* src = tile + ((w * 2 + j) * 64 + lane) * 4;
    __builtin_amdgcn_global_load_lds((GU*)src, (LU*)(lbuf + (w * 2 + j) * 256),
                                     16, 0, 0);
  }
}

// 8 MFMA from swizzled LDS tile (B rows = tokens for QK / dims for PV)
DEV void mm8_lds(const unsigned* buf, const s8_t A[2], int qi, int g, f4_t c[4]) {
#pragma unroll
  for (int t = 0; t < 4; ++t) {
    f4_t acc = {0.f, 0.f, 0.f, 0.f};
#pragma unroll
    for (int ks = 0; ks < 2; ++ks) {
      const s8_t B = as_s8(*(const uint4*)(buf + swz(t * 16 + qi, ks * 4 + g)));
      acc = mfma16(A[ks], B, acc);
    }
    c[t] = acc;
  }
}
DEV void mm8acc_lds(const unsigned* buf, const s8_t A[2], int qi, int g, f4_t Of[4]) {
#pragma unroll
  for (int ks = 0; ks < 2; ++ks) {
#pragma unroll
    for (int t = 0; t < 4; ++t) {
      const s8_t B = as_s8(*(const uint4*)(buf + swz(t * 16 + qi, ks * 4 + g)));
      Of[t] = mfma16(A[ks], B, Of[t]);
    }
  }
}

// redistribute C frags (q rows 0..7) -> per-lane raw[j], lane = col 0..63.
DEV void redist(const f4_t c[4], float* scw, int lane, float raw[8]) {
  if (lane < 32) {
    const int g2 = lane >> 4, ci = lane & 15;
#pragma unroll
    for (int t = 0; t < 4; ++t)
      *(f4_t*)(scw + (t * 16 + ci) * 8 + g2 * 4) = c[t];
  }
  wave_fence();
  *(f4_t*)(raw)     = *(const f4_t*)(scw + lane * 8);
  *(f4_t*)(raw + 4) = *(const f4_t*)(scw + lane * 8 + 4);
}

// ---- ws layout (4-byte element offsets) ----
constexpr size_t OFF_KBLK  = 0;         // f32 16*32*64
constexpr size_t OFF_VBLK  = 32768;     // f32 16*32*64
constexpr size_t OFF_SEL   = 65536;     // int 16*32*8
constexpr size_t OFF_KBAR  = 69632;     // u32 16*2048 (swizzled tiles)
constexpr size_t OFF_VBART = 102400;    // u32 16*2048
constexpr size_t OFF_K16   = 135168;    // u32 16*32*2048
constexpr size_t OFF_VT16  = 1183744;   // u32 16*32*2048

// ---------------------------------------------------------------------------
// Prep 1: bf16 swizzled K/V tiles + exact f32 block means
__global__ __launch_bounds__(256) void nsa_cvt(
    const float* __restrict__ kg, const float* __restrict__ vg,
    float* __restrict__ kblk, float* __restrict__ vblk,
    unsigned* __restrict__ K16, unsigned* __restrict__ VT16) {
  const int blk = blockIdx.x, bh = blockIdx.y, tid = threadIdx.x;
  __shared__ float kl[64][65], vl[64][65];
  const size_t tb = ((size_t)bh * SS + (size_t)blk * BS) * DD;
  unsigned* Kt = K16 + ((size_t)bh * NBLK + blk) * 2048;
  unsigned* Vt = VT16 + ((size_t)bh * NBLK + blk) * 2048;
#pragma unroll
  for (int m = 0; m < 4; ++m) {
    const int f4i = tid + 256 * m;
    const int r = f4i >> 4, c = f4i & 15;
    const float4 kk = *(const float4*)(kg + tb + r * DD + c * 4);
    const float4 vv = *(const float4*)(vg + tb + r * DD + c * 4);
    kl[r][c * 4] = kk.x; kl[r][c * 4 + 1] = kk.y;
    kl[r][c * 4 + 2] = kk.z; kl[r][c * 4 + 3] = kk.w;
    vl[r][c * 4] = vv.x; vl[r][c * 4 + 1] = vv.y;
    vl[r][c * 4 + 2] = vv.z; vl[r][c * 4 + 3] = vv.w;
    const int a = r * 32 + (((c >> 1) ^ (r & 7)) << 2) + (c & 1) * 2;
    Kt[a]     = cvt_pk(kk.x, kk.y);
    Kt[a + 1] = cvt_pk(kk.z, kk.w);
  }
  __syncthreads();
  const int d = tid >> 2, cg = tid & 3;
#pragma unroll
  for (int cc = 0; cc < 2; ++cc) {
    const int c = cg * 2 + cc;
#pragma unroll
    for (int w4 = 0; w4 < 4; ++w4) {
      const int tp = c * 4 + w4;
      Vt[d * 32 + ((c ^ (d & 7)) << 2) + w4] = cvt_pk(vl[2 * tp][d], vl[2 * tp + 1][d]);
    }
  }
  if (tid < DD) {
    float sk = 0.f, sv = 0.f;
#pragma unroll 8
    for (int t = 0; t < BS; ++t) { sk += kl[t][tid]; sv += vl[t][tid]; }
    kblk[((size_t)bh * NBLK + blk) * DD + tid] = sk * (1.f / 64.f);
    vblk[((size_t)bh * NBLK + blk) * DD + tid] = sv * (1.f / 64.f);
  }
}

// ---------------------------------------------------------------------------
// Prep 2 (tiny, parallel): K̄/V̄T swizzled tiles per bh (k0/v0 folded).
__global__ __launch_bounds__(256) void nsa_bar(
    const float* __restrict__ kg, const float* __restrict__ vg,
    const float* __restrict__ kblk, const float* __restrict__ vblk,
    unsigned* __restrict__ Kbar16, unsigned* __restrict__ VbarT16) {
  const int bh = blockIdx.x, tid = threadIdx.x;
  unsigned* Kt = Kbar16 + (size_t)bh * 2048;
  unsigned* Vt = VbarT16 + (size_t)bh * 2048;
  for (int i = tid; i < 2048; i += 256) {
    const int n = i >> 5, c = i & 31;
    unsigned u = 0u;
    if (n < 32)
      u = cvt_pk(kblk[((size_t)bh * NBLK + n) * DD + 2 * c],
                 kblk[((size_t)bh * NBLK + n) * DD + 2 * c + 1]);
    else if (n == 32)
      u = cvt_pk(kg[(size_t)bh * SS * DD + 2 * c],
                 kg[(size_t)bh * SS * DD + 2 * c + 1]);
    Kt[n * 32 + (((c >> 2) ^ (n & 7)) << 2) + (c & 3)] = u;
  }
  for (int i = tid; i < 2048; i += 256) {
    const int d = i >> 5, tp = i & 31;
    unsigned u = 0u;
    if (tp < 16)
      u = cvt_pk(vblk[((size_t)bh * NBLK + 2 * tp) * DD + d],
                 vblk[((size_t)bh * NBLK + 2 * tp + 1) * DD + d]);
    else if (tp == 16)
      u = cvt_pk(vg[(size_t)bh * SS * DD + d], 0.f);
    Vt[d * 32 + (((tp >> 2) ^ (d & 7)) << 2) + (tp & 3)] = u;
  }
}

// ---------------------------------------------------------------------------
// Prep 3 (parallel selection — R17's proven prologue extracted):
// 4-wave partial Q sums -> wave-0 factorized scores + top-8 (exact
// lax.top_k tie-break). grid (32, 16), 256 threads.
__global__ __launch_bounds__(256) void nsa_sel(
    const float* __restrict__ qg, const float* __restrict__ kblk,
    int* __restrict__ selidx) {
  const int gp = blockIdx.x, bh = blockIdx.y, tid = threadIdx.x;
  const int w = tid >> 6, lane = tid & 63;
  __shared__ float partial_s[4][64];
  __shared__ float qb_s[64];
  {
    const float* qp = qg + ((size_t)bh * SS + (size_t)gp * 64 + w * 16) * DD + lane;
    float s = 0.f;
#pragma unroll 4
    for (int r = 0; r < 16; ++r) s += qp[r * DD];
    partial_s[w][lane] = s;
  }
  __syncthreads();
  if (w == 0) {
    qb_s[lane] = partial_s[0][lane] + partial_s[1][lane] +
                 partial_s[2][lane] + partial_s[3][lane];
    wave_fence();
    const int n2 = lane & 31, half = lane >> 5;
    const float* kr = kblk + ((size_t)bh * NBLK + n2) * DD + half * 32;
    float p = 0.f;
#pragma unroll
    for (int dd = 0; dd < 32; ++dd) p = fmaf(qb_s[half * 32 + dd], kr[dd], p);
    p += __shfl_xor(p, 32, 64);
    float s = (lane < 32) ? ((n2 <= gp) ? p : NEGINF) : -3.4e38f;
    const int bi = lane;
    for (int t = 0; t < SNB; ++t) {
      float bs = s; int bb = bi;
#pragma unroll
      for (int o = 32; o > 0; o >>= 1) {
        const float os = __shfl_xor(bs, o, 64);
        const int   ob = __shfl_xor(bb, o, 64);
        if (os > bs || (os == bs && ob < bb)) { bs = os; bb = ob; }
      }
      if (lane == 0) selidx[((size_t)bh * NBLK + gp) * SNB + t] = bb;
      if (bi == bb) s = -3.4e38f;
    }
  }
}

// ---------------------------------------------------------------------------
// Main: 24 stages, ring-3 staging, counted vmcnt (fused barriers),
// XCD-swizzled 1D grid. (R16's exact main.)
__global__ __launch_bounds__(256) void nsa_main(
    const float* __restrict__ qg, const int* __restrict__ selp,
    const unsigned* __restrict__ Kbar16, const unsigned* __restrict__ VbarT16,
    const unsigned* __restrict__ K16, const unsigned* __restrict__ VT16,
    float* __restrict__ outg) {
  const int tid  = threadIdx.x;
  const int w    = tid >> 6;
  const int lane = tid & 63;
  // XCD-aware swizzle: XCD i (lin%8) owns bh pair {2i,2i+1}. Bijective.
  const int lin  = blockIdx.x;
  const int virt = (lin & 7) * 128 + (lin >> 3);
  const int bh   = virt >> 6;
  const int xblk = virt & 63;
  const int qtile = xblk * 4 + w;           // 0..255 (8 queries each)
  const int gg    = xblk >> 1;              // 64-query group (block-uniform)
  const int q0    = qtile * 8;
  const size_t base = (size_t)bh * SS * DD;

  __shared__ __align__(16) unsigned buf_s[3][2048];  // 24 KB ring
  __shared__ __align__(16) float sc_f[4][576];       // per-wave scratch
  float* scw = sc_f[w];
  unsigned short* scwu = (unsigned short*)scw;
  const int qi = lane & 15, g = lane >> 4;
  const int qc = (qi < 8) ? qi : 0;

  const unsigned* K16b = K16 + (size_t)bh * NBLK * 2048;
  const unsigned* V16b = VT16 + (size_t)bh * NBLK * 2048;
  const int wb0 = (gg > 2) ? gg - 2 : 0;
  const int wb1 = (gg > 1) ? gg - 1 : 0;
  const int wb2 = gg;

  // ---- prologue: sel list, Q frags, first two tile DMAs ----
  int sel[SNB];
#pragma unroll
  for (int i = 0; i < SNB; ++i) sel[i] = selp[((size_t)bh * NBLK + gg) * SNB + i];
  s8_t qA[2];
  {
    const float* qr2 = qg + base + (size_t)(q0 + qc) * DD + g * 8;
    const float4 a0 = *(const float4*)(qr2);
    const float4 a1 = *(const float4*)(qr2 + 4);
    const float4 a2 = *(const float4*)(qr2 + 32);
    const float4 a3 = *(const float4*)(qr2 + 36);
    uint4 u0 = {cvt_pk(a0.x, a0.y), cvt_pk(a0.z, a0.w),
                cvt_pk(a1.x, a1.y), cvt_pk(a1.z, a1.w)};
    uint4 u1 = {cvt_pk(a2.x, a2.y), cvt_pk(a2.z, a2.w),
                cvt_pk(a3.x, a3.y), cvt_pk(a3.z, a3.w)};
    qA[0] = (qi < 8) ? as_s8(u0) : s8zero();
    qA[1] = (qi < 8) ? as_s8(u1) : s8zero();
  }
  // tiles 0 (K̄) and 1 (K sel[0])
  stage_dma(Kbar16 + (size_t)bh * 2048, buf_s[0], w, lane);
  stage_dma(K16b + (size_t)sel[0] * 2048, buf_s[1], w, lane);

  // ================= K phase =================
  unsigned cPp[4];
  float l192[8];
  // --- stage 0: K̄ (+k0 col 32) ---
  dma_bar2();
  stage_dma(K16b + (size_t)sel[1] * 2048, buf_s[2], w, lane);   // tile 2
  {
    f4_t c[4];
    mm8_lds(buf_s[0], qA, qi, g, c);
    float raw[8];
    redist(c, scw, lane, raw);
    float cPf[8];
#pragma unroll
    for (int j = 0; j < 8; ++j) {
      l192[j] = readlane_f(raw[j], 32) * SCALE;
      const bool valid = (lane < 32) && (lane <= gg);
      const float l = valid ? raw[j] * SCALE : NEGINF;
      const float m = wave_max(l);
      const float e = valid ? __expf(l - m) : 0.f;
      const float ss = wave_sum(e);
      cPf[j] = e / ss;
    }
#pragma unroll
    for (int ip = 0; ip < 4; ++ip) cPp[ip] = cvt_pk(cPf[2 * ip], cPf[2 * ip + 1]);
  }

  // --- stages 1..8: sel QK ---
  float L[8][SNB];
#pragma unroll
  for (int sbi = 0; sbi < SNB; ++sbi) {
    const int s = 1 + sbi;
    dma_bar2();
    const unsigned* nt = (sbi <= 5) ? (K16b + (size_t)sel[sbi + 2] * 2048)
                       : ((sbi == 6) ? (K16b + (size_t)wb0 * 2048)
                                     : (K16b + (size_t)wb1 * 2048));
    stage_dma(nt, buf_s[(s + 2) % 3], w, lane);
    f4_t c[4];
    mm8_lds(buf_s[s % 3], qA, qi, g, c);
    float raw[8];
    redist(c, scw, lane, raw);
    const int tok = sel[sbi] * BS + lane;
#pragma unroll
    for (int j = 0; j < 8; ++j)
      L[j][sbi] = (tok <= q0 + j) ? raw[j] * SCALE : NEGINF;
  }

  // ---- threshold (12-iter float-window) + sel softmax -> packed bf16 ----
  unsigned Lp[8][4];
#pragma unroll
  for (int j = 0; j < 8; ++j) {
    float m = L[j][0];
#pragma unroll
    for (int i = 1; i < SNB; ++i) m = fmaxf(m, L[j][i]);
    m = wave_max(m);
    float lo = m - 20.f, hi = m;
    int c0 = 0;
#pragma unroll
    for (int i = 0; i < SNB; ++i) c0 += __popcll(__ballot(L[j][i] >= lo));
    if (c0 >= KKEEP) {
      for (int it = 0; it < 12; ++it) {
        const float mid = 0.5f * (lo + hi);
        int cc = 0;
#pragma unroll
        for (int i = 0; i < SNB; ++i) cc += __popcll(__ballot(L[j][i] >= mid));
        if (cc >= KKEEP) lo = mid; else hi = mid;
      }
    }
    const float thr = lo;
    float s = 0.f;
#pragma unroll
    for (int i = 0; i < SNB; ++i) {
      const float e = (L[j][i] >= thr) ? __expf(L[j][i] - m) : 0.f;
      L[j][i] = e; s += e;
    }
    s = wave_sum(s);
    const float inv = 1.f / s;
#pragma unroll
    for (int ip = 0; ip < 4; ++ip)
      Lp[j][ip] = cvt_pk(L[j][2 * ip] * inv, L[j][2 * ip + 1] * inv);
  }

  // --- stages 9..11: win QK ---
  float Lw[8][3];
#pragma unroll
  for (int wi = 0; wi < 3; ++wi) {
    const int s = 9 + wi;
    const int wb = gg - 2 + wi;
    dma_bar2();
    const unsigned* nt = (wi == 0) ? (K16b + (size_t)wb2 * 2048)
                       : ((wi == 1) ? (VbarT16 + (size_t)bh * 2048)
                                    : (V16b + (size_t)sel[0] * 2048));
    stage_dma(nt, buf_s[(s + 2) % 3], w, lane);
    f4_t c[4];
    mm8_lds(buf_s[s % 3], qA, qi, g, c);
    float raw[8];
    redist(c, scw, lane, raw);
    const int tok = wb * BS + lane;
#pragma unroll
    for (int j = 0; j < 8; ++j) {
      const int pos = q0 + j;
      const bool valid = (wb >= 0) && (tok <= pos) && ((pos - tok < 128) || (tok == 0));
      Lw[j][wi] = valid ? raw[j] * SCALE : NEGINF;
    }
  }

  // ---- win softmax ----
  unsigned Lwp[8][2];
  float p192[8];
#pragma unroll
  for (int j = 0; j < 8; ++j) {
    const float l1 = (gg >= 3) ? l192[j] : NEGINF;
    float m = fmaxf(fmaxf(Lw[j][0], Lw[j][1]), Lw[j][2]);
    m = wave_max(m);
    m = fmaxf(m, l1);
    const float e0 = __expf(Lw[j][0] - m);
    const float e1 = __expf(Lw[j][1] - m);
    const float e2 = __expf(Lw[j][2] - m);
    float s = wave_sum(e0 + e1 + e2);
    const float e192 = (gg >= 3) ? __expf(l1 - m) : 0.f;
    s += e192;
    const float inv = 1.f / s;
    Lwp[j][0] = cvt_pk(e0 * inv, e1 * inv);
    Lwp[j][1] = cvt_pk(e2 * inv, 0.f);
    p192[j] = e192 * inv;
  }

  // ================= V phase =================
  f4_t Of[4];
#pragma unroll
  for (int t = 0; t < 4; ++t) Of[t] = (f4_t){0.f, 0.f, 0.f, 0.f};
  s8_t Pa[2];

  // --- stage 12: V̄ (cmp PV + global token at tok 32) ---
  dma_bar2();
  stage_dma(V16b + (size_t)sel[1] * 2048, buf_s[(12 + 2) % 3], w, lane); // tile 14
#pragma unroll
  for (int j = 0; j < 8; ++j) {
    const unsigned uu = cPp[j >> 1];
    unsigned short pv = (unsigned short)((j & 1) ? (uu >> 16) : (uu & 0xffffu));
    if (lane == 32) pv = (unsigned short)(cvt_pk(p192[j], 0.f) & 0xffffu);
    else if (lane > 32) pv = 0;
    scwu[j * 136 + lane] = pv;
  }
  wave_fence();
#pragma unroll
  for (int ks = 0; ks < 2; ++ks) {
    Pa[ks] = as_s8(*(const uint4*)(scwu + qc * 136 + ks * 32 + g * 8));
    if (qi >= 8) Pa[ks] = s8zero();
  }
  mm8acc_lds(buf_s[12 % 3], Pa, qi, g, Of);

  // --- stages 13..20: sel PV ---
#pragma unroll
  for (int sbi = 0; sbi < SNB; ++sbi) {
    const int s = 13 + sbi;
    dma_bar2();
    const unsigned* nt = (sbi <= 5) ? (V16b + (size_t)sel[sbi + 2] * 2048)
                       : ((sbi == 6) ? (V16b + (size_t)wb0 * 2048)
                                     : (V16b + (size_t)wb1 * 2048));
    stage_dma(nt, buf_s[(s + 2) % 3], w, lane);
#pragma unroll
    for (int j = 0; j < 8; ++j) {
      const unsigned uu = Lp[j][sbi >> 1];
      scwu[j * 136 + lane] = (unsigned short)((sbi & 1) ? (uu >> 16) : (uu & 0xffffu));
    }
    wave_fence();
#pragma unroll
    for (int ks = 0; ks < 2; ++ks) {
      Pa[ks] = as_s8(*(const uint4*)(scwu + qc * 136 + ks * 32 + g * 8));
      if (qi >= 8) Pa[ks] = s8zero();
    }
    mm8acc_lds(buf_s[s % 3], Pa, qi, g, Of);
  }

  // --- stages 21..23: win PV ---
#pragma unroll
  for (int wi = 0; wi < 3; ++wi) {
    const int s = 21 + wi;
    if (wi == 0) {
      dma_bar2();
      stage_dma(V16b + (size_t)wb2 * 2048, buf_s[(s + 2) % 3], w, lane); // tile 23
    } else if (wi == 1) {
      dma_bar2();
    } else {
      dma_bar0();   // drain: last tile must be fully landed
    }
#pragma unroll
    for (int j = 0; j < 8; ++j) {
      const unsigned uu = Lwp[j][wi >> 1];
      scwu[j * 136 + lane] = (unsigned short)((wi & 1) ? (uu >> 16) : (uu & 0xffffu));
    }
    wave_fence();
#pragma unroll
    for (int ks = 0; ks < 2; ++ks) {
      Pa[ks] = as_s8(*(const uint4*)(scwu + qc * 136 + ks * 32 + g * 8));
      if (qi >= 8) Pa[ks] = s8zero();
    }
    mm8acc_lds(buf_s[s % 3], Pa, qi, g, Of);
  }

  // ---- epilogue: Of -> lane=dim, store (cmp+sel+win+global)/3 ----
  float ofin[8];
  redist(Of, scw, lane, ofin);
#pragma unroll
  for (int j = 0; j < 8; ++j)
    outg[base + (size_t)(q0 + j) * DD + lane] = ofin[j] * (1.f / 3.f);
}

// ---------------------------------------------------------------------------
extern "C" void kernel_launch(void* const* d_in, const int* in_sizes, int n_in,
                              void* d_out, int out_size, void* d_ws, size_t ws_size,
                              hipStream_t stream) {
  (void)in_sizes; (void)n_in; (void)out_size; (void)ws_size;
  const float* q = (const float*)d_in[0];
  const float* k = (const float*)d_in[1];
  const float* v = (const float*)d_in[2];
  float* out = (float*)d_out;

  float*    wsf   = (float*)d_ws;
  float*    kblk  = wsf + OFF_KBLK;
  float*    vblk  = wsf + OFF_VBLK;
  int*      selI  = (int*)d_ws + OFF_SEL;
  unsigned* Kbar  = (unsigned*)d_ws + OFF_KBAR;
  unsigned* VbarT = (unsigned*)d_ws + OFF_VBART;
  unsigned* K16   = (unsigned*)d_ws + OFF_K16;
  unsigned* VT16  = (unsigned*)d_ws + OFF_VT16;

  dim3 g1(NBLK, 16);
  nsa_cvt<<<g1, 256, 0, stream>>>(k, v, kblk, vblk, K16, VT16);
  nsa_bar<<<dim3(16), 256, 0, stream>>>(k, v, kblk, vblk, Kbar, VbarT);
  dim3 g2(NBLK, 16);
  nsa_sel<<<g2, 256, 0, stream>>>(q, kblk, selI);
  nsa_main<<<dim3(1024), 256, 0, stream>>>(q, selI, Kbar, VbarT, K16, VT16, out);
}